// Round 5
// baseline (1206.216 us; speedup 1.0000x reference)
//
#include <hip/hip_runtime.h>

#define T_DIM 4096
#define D_DIM 2048
#define H_DIM 32
#define DH    64
#define CHUNK 64
#define NCHUNK (T_DIM / CHUNK)
#define EPS 1e-5f

typedef __attribute__((ext_vector_type(8))) short short8;
typedef __attribute__((ext_vector_type(4))) float f32x4;

// ----------------------------------------------------------- bf16 split utils
__device__ inline ushort f2bf(float f) {
  uint u = __float_as_uint(f);
  u += 0x7FFF + ((u >> 16) & 1);          // RNE
  return (ushort)(u >> 16);
}
__device__ inline float bf2f(ushort h) { return __uint_as_float(((uint)h) << 16); }
__device__ inline void split2(float f, ushort& hi, ushort& lo) {
  hi = f2bf(f);
  lo = f2bf(f - bf2f(hi));
}

// ------------------------------------------------------ global->LDS async DMA
// LDS dest = wave-uniform base + lane*16B (m97/m104-verified semantics).
__device__ __forceinline__ void gload16(const void* g, void* lds) {
  __builtin_amdgcn_global_load_lds(
      (const __attribute__((address_space(1))) unsigned int*)g,
      (__attribute__((address_space(3))) unsigned int*)lds, 16, 0, 0);
}

// ---------------------------------------------------------------- LN helper
__device__ inline void block_reduce_2(float& s1, float& s2) {
  __shared__ float red[8];
  #pragma unroll
  for (int off = 32; off > 0; off >>= 1) {
    s1 += __shfl_down(s1, off, 64);
    s2 += __shfl_down(s2, off, 64);
  }
  int lane = threadIdx.x & 63, wid = threadIdx.x >> 6;
  if (lane == 0) { red[wid] = s1; red[4 + wid] = s2; }
  __syncthreads();
  s1 = red[0] + red[1] + red[2] + red[3];
  s2 = red[4] + red[5] + red[6] + red[7];
}

// LN over rows of length D_DIM; emits SPLIT bf16 (hi, lo) for GEMM A-input.
// If Add != nullptr: input = X + Add, pre-LN sum stored fp32 to Yout
// (Yout may alias Add: same-thread read-before-write at same offsets).
__global__ __launch_bounds__(256) void ln_fwd(
    const float* __restrict__ X, const float* Add, float* Yout,
    const float* __restrict__ w, const float* __restrict__ b,
    ushort* __restrict__ out_hi, ushort* __restrict__ out_lo) {
  const int row = blockIdx.x;
  const size_t base = (size_t)row * D_DIM;
  const int t = threadIdx.x;

  float4 v0 = *(const float4*)(X + base + (size_t)t * 4);
  float4 v1 = *(const float4*)(X + base + (size_t)(t + 256) * 4);
  if (Add) {
    float4 a0 = *(const float4*)(Add + base + (size_t)t * 4);
    float4 a1 = *(const float4*)(Add + base + (size_t)(t + 256) * 4);
    v0.x += a0.x; v0.y += a0.y; v0.z += a0.z; v0.w += a0.w;
    v1.x += a1.x; v1.y += a1.y; v1.z += a1.z; v1.w += a1.w;
    *(float4*)(Yout + base + (size_t)t * 4) = v0;
    *(float4*)(Yout + base + (size_t)(t + 256) * 4) = v1;
  }
  float s  = v0.x + v0.y + v0.z + v0.w + v1.x + v1.y + v1.z + v1.w;
  float ss = v0.x*v0.x + v0.y*v0.y + v0.z*v0.z + v0.w*v0.w
           + v1.x*v1.x + v1.y*v1.y + v1.z*v1.z + v1.w*v1.w;
  block_reduce_2(s, ss);
  const float m   = s * (1.0f / D_DIM);
  const float var = ss * (1.0f / D_DIM) - m * m;
  const float r   = rsqrtf(var + EPS);

  float4 w0 = *(const float4*)(w + (size_t)t * 4);
  float4 w1 = *(const float4*)(w + (size_t)(t + 256) * 4);
  float4 b0 = *(const float4*)(b + (size_t)t * 4);
  float4 b1 = *(const float4*)(b + (size_t)(t + 256) * 4);
  float o[8];
  o[0] = (v0.x - m) * r * w0.x + b0.x;
  o[1] = (v0.y - m) * r * w0.y + b0.y;
  o[2] = (v0.z - m) * r * w0.z + b0.z;
  o[3] = (v0.w - m) * r * w0.w + b0.w;
  o[4] = (v1.x - m) * r * w1.x + b1.x;
  o[5] = (v1.y - m) * r * w1.y + b1.y;
  o[6] = (v1.z - m) * r * w1.z + b1.z;
  o[7] = (v1.w - m) * r * w1.w + b1.w;
  ushort h[8], l[8];
  #pragma unroll
  for (int j = 0; j < 8; ++j) split2(o[j], h[j], l[j]);
  *(ushort4*)(out_hi + base + (size_t)t * 4) = make_ushort4(h[0], h[1], h[2], h[3]);
  *(ushort4*)(out_lo + base + (size_t)t * 4) = make_ushort4(l[0], l[1], l[2], l[3]);
  *(ushort4*)(out_hi + base + (size_t)(t + 256) * 4) = make_ushort4(h[4], h[5], h[6], h[7]);
  *(ushort4*)(out_lo + base + (size_t)(t + 256) * 4) = make_ushort4(l[4], l[5], l[6], l[7]);
}

// ----------------------------------- weight transpose + bf16 split (JIT, 64x64)
// W [KR][NC] fp32 -> WT_hi/WT_lo [NC][KR] bf16
__global__ __launch_bounds__(256) void tsplit(
    const float* __restrict__ W, ushort* __restrict__ WTh,
    ushort* __restrict__ WTl, int KR, int NC) {
  __shared__ float tile[64][65];
  const int t = threadIdx.x;
  const int k0 = blockIdx.y * 64, n0 = blockIdx.x * 64;
  #pragma unroll
  for (int p = 0; p < 4; ++p) {
    int r = (t >> 4) + p * 16;
    int c = (t & 15) * 4;
    *(float4*)&tile[r][c] = *(const float4*)&W[(size_t)(k0 + r) * NC + n0 + c];
  }
  __syncthreads();
  #pragma unroll
  for (int p = 0; p < 4; ++p) {
    int n = (t >> 4) + p * 16;       // local out row (n)
    int c = (t & 15) * 4;            // local out col base (k)
    ushort h[4], l[4];
    #pragma unroll
    for (int j = 0; j < 4; ++j) split2(tile[c + j][n], h[j], l[j]);
    size_t off = (size_t)(n0 + n) * KR + k0 + c;
    *(ushort4*)(WTh + off) = make_ushort4(h[0], h[1], h[2], h[3]);
    *(ushort4*)(WTl + off) = make_ushort4(l[0], l[1], l[2], l[3]);
  }
}

// ------------------------------------------- split-bf16 MFMA GEMM (3 products)
// C[M,N] = A[M,K] @ B[K,N] (+Add), A as hi/lo bf16 [M][K], B as TRANSPOSED
// hi/lo bf16 [N][K]. C fp32 (may alias Add).
// m97 structure: global_load_lds staging, single-buffered, 2 barriers/K-step.
// 128x64 tile, 4 waves (each 64x32 output), BK=32.
// LDS linear [row][32k] (64B rows); k-quarter XOR swizzle applied on BOTH the
// global source (q = (l&3)^((l>>3)&3)) and the frag-read slot -> involution
// cancels (lanes read true global k-order), reads are 2-way (free, m136).
#define BM 128
#define BN 64
#define BK 32
__global__ __launch_bounds__(256) void gemm_bf16s(
    const ushort* __restrict__ Ah, const ushort* __restrict__ Al,
    const ushort* __restrict__ Bh, const ushort* __restrict__ Bl,
    const float* Add, float* __restrict__ C, int M, int N, int K) {
  __shared__ ushort Ash[BM * BK];   // 8KB
  __shared__ ushort Asl[BM * BK];   // 8KB
  __shared__ ushort Bsh[BN * BK];   // 4KB
  __shared__ ushort Bsl[BN * BK];   // 4KB   total 24KB
  const int tid = threadIdx.x;

  // Bijective XCD-aware swizzle of flattened block id (grids are %8==0).
  int bxs = blockIdx.x, bys = blockIdx.y;
  {
    int gx = gridDim.x, n = gx * gridDim.y;
    int lid = bys * gx + bxs;
    if ((n & 7) == 0) {
      int cpx = n >> 3;
      lid = (lid & 7) * cpx + (lid >> 3);
      bys = lid / gx;
      bxs = lid - bys * gx;
    }
  }
  const int bm = bys * BM, bn = bxs * BN;

  const int l = tid & 63, wv = tid >> 6;
  const int lrow = l >> 2;                       // staging: row within 16-row chunk
  const int q = (l & 3) ^ ((l >> 3) & 3);        // pre-swizzled global k-quarter
  const int ln = l & 15, kg = l >> 4;
  const int xs = (kg ^ ((ln >> 1) & 3)) * 8;     // swizzled frag slot (ushorts)
  const int wm_ = (wv >> 1) * 64, wn_ = (wv & 1) * 32;

  f32x4 acc[4][2];
  #pragma unroll
  for (int i = 0; i < 4; ++i)
    #pragma unroll
    for (int j = 0; j < 2; ++j) {
      f32x4 z = {0.f, 0.f, 0.f, 0.f};
      acc[i][j] = z;
    }

  for (int k0 = 0; k0 < K; k0 += BK) {
    // ---- stage: 6 global_load_lds_dwordx4 per wave (A:2+2, B:1+1)
    {
      size_t ga = (size_t)(bm + wv * 32 + lrow) * K + k0 + q * 8;
      gload16(Ah + ga,          &Ash[(wv * 32) * BK]);
      gload16(Ah + ga + 16 * (size_t)K, &Ash[(wv * 32 + 16) * BK]);
      gload16(Al + ga,          &Asl[(wv * 32) * BK]);
      gload16(Al + ga + 16 * (size_t)K, &Asl[(wv * 32 + 16) * BK]);
      size_t gb = (size_t)(bn + wv * 16 + lrow) * K + k0 + q * 8;
      gload16(Bh + gb, &Bsh[(wv * 16) * BK]);
      gload16(Bl + gb, &Bsl[(wv * 16) * BK]);
    }
    __syncthreads();   // compiler emits vmcnt(0) drain before s_barrier

    short8 fah[4], fal[4], fbh[2], fbl[2];
    #pragma unroll
    for (int i = 0; i < 4; ++i) {
      fah[i] = *(const short8*)&Ash[(wm_ + i * 16 + ln) * BK + xs];
      fal[i] = *(const short8*)&Asl[(wm_ + i * 16 + ln) * BK + xs];
    }
    #pragma unroll
    for (int j = 0; j < 2; ++j) {
      fbh[j] = *(const short8*)&Bsh[(wn_ + j * 16 + ln) * BK + xs];
      fbl[j] = *(const short8*)&Bsl[(wn_ + j * 16 + ln) * BK + xs];
    }
    #pragma unroll
    for (int i = 0; i < 4; ++i)
      #pragma unroll
      for (int j = 0; j < 2; ++j) {
        acc[i][j] = __builtin_amdgcn_mfma_f32_16x16x32_bf16(fah[i], fbh[j], acc[i][j], 0, 0, 0);
        acc[i][j] = __builtin_amdgcn_mfma_f32_16x16x32_bf16(fah[i], fbl[j], acc[i][j], 0, 0, 0);
        acc[i][j] = __builtin_amdgcn_mfma_f32_16x16x32_bf16(fal[i], fbh[j], acc[i][j], 0, 0, 0);
      }
    __syncthreads();   // protect LDS from next-iter staging
  }

  // epilogue: C/D layout col=lane&15, row=(lane>>4)*4+reg (m89-verified)
  #pragma unroll
  for (int i = 0; i < 4; ++i)
    #pragma unroll
    for (int j = 0; j < 2; ++j) {
      #pragma unroll
      for (int rg = 0; rg < 4; ++rg) {
        int row = bm + wm_ + i * 16 + kg * 4 + rg;
        int col = bn + wn_ + j * 16 + ln;
        size_t off = (size_t)row * N + col;
        float v = acc[i][j][rg];
        if (Add) v += Add[off];
        C[off] = v;
      }
    }
}

// ------------------------------------------------- per-chunk  sum k_s (x) v_s
__global__ __launch_bounds__(256) void chunk_kv_sums(
    const float* __restrict__ Km, const float* __restrict__ Vm,
    float* __restrict__ S) {
  __shared__ float Ks[CHUNK][DH];
  __shared__ float Vs[CHUNK][DH];
  const int c = blockIdx.x, hh = blockIdx.y, tid = threadIdx.x;
  #pragma unroll
  for (int l = 0; l < 4; ++l) {
    int idx = tid + l * 256;
    int s = idx >> 4, c4 = (idx & 15) << 2;
    size_t g = (size_t)(c * CHUNK + s) * D_DIM + hh * DH + c4;
    *(float4*)&Ks[s][c4] = *(const float4*)(Km + g);
    *(float4*)&Vs[s][c4] = *(const float4*)(Vm + g);
  }
  __syncthreads();
  const int i0 = (tid >> 4) << 2;
  const int j0 = (tid & 15) << 2;
  float acc[4][4] = {};
  for (int s = 0; s < CHUNK; ++s) {
    float kv[4], vv[4];
    *(float4*)kv = *(const float4*)&Ks[s][i0];
    *(float4*)vv = *(const float4*)&Vs[s][j0];
    #pragma unroll
    for (int ii = 0; ii < 4; ++ii)
      #pragma unroll
      for (int jj = 0; jj < 4; ++jj)
        acc[ii][jj] = fmaf(kv[ii], vv[jj], acc[ii][jj]);
  }
  const size_t base = ((size_t)c * H_DIM + hh) * (DH * DH);
  #pragma unroll
  for (int ii = 0; ii < 4; ++ii)
    *(float4*)&S[base + (size_t)(i0 + ii) * DH + j0] =
        make_float4(acc[ii][0], acc[ii][1], acc[ii][2], acc[ii][3]);
}

// --------------------------- exclusive prefix over chunks (in place) + final
__global__ __launch_bounds__(256) void state_scan(
    const float* __restrict__ st0, const float* __restrict__ gamma,
    float* __restrict__ S, float* __restrict__ fs_out) {
  const int hh = blockIdx.y;
  const int e = blockIdx.x * 256 + threadIdx.x;
  float run = st0[(size_t)hh * 4096 + e];
  for (int c = 0; c < NCHUNK; ++c) {
    size_t idx = ((size_t)c * H_DIM + hh) * 4096 + e;
    float tmp = S[idx];
    S[idx] = run;
    run += tmp;
  }
  const int i = e >> 6;
  fs_out[(size_t)hh * 4096 + e] = run + (float)T_DIM * gamma[hh * DH + i];
}

// ------------------------------------------------------- per-chunk attention
__global__ __launch_bounds__(256) void attn_intra(
    const float* __restrict__ Qm, const float* __restrict__ Km,
    const float* __restrict__ Vm, const float* __restrict__ M,
    const float* __restrict__ gamma, float* __restrict__ O) {
  __shared__ float Qs[CHUNK * DH];
  __shared__ float Bf[CHUNK * DH];
  __shared__ float As[CHUNK * CHUNK];
  __shared__ float Sq[CHUNK];
  const int c = blockIdx.x, hh = blockIdx.y, tid = threadIdx.x;

  #pragma unroll
  for (int l = 0; l < 4; ++l) {
    int idx = tid + l * 256;
    int r = idx >> 4, c4 = (idx & 15) << 2;
    size_t g = (size_t)(c * CHUNK + r) * D_DIM + hh * DH + c4;
    *(float4*)&Qs[r * DH + c4] = *(const float4*)(Qm + g);
    float4 vv = *(const float4*)(Vm + g);
    Bf[(c4 + 0) * CHUNK + r] = vv.x;
    Bf[(c4 + 1) * CHUNK + r] = vv.y;
    Bf[(c4 + 2) * CHUNK + r] = vv.z;
    Bf[(c4 + 3) * CHUNK + r] = vv.w;
  }
  __syncthreads();
  if (tid < CHUNK) {
    float s = 0.f;
    for (int j = 0; j < DH; ++j) s += Qs[tid * DH + j];
    Sq[tid] = s;
  }
  #pragma unroll
  for (int rr = 0; rr < 16; ++rr) {
    int p = tid + rr * 256;
    int t = p >> 6, s = p & 63;
    float a = 0.f;
    for (int j = 0; j < DH; ++j)
      a = fmaf(Qs[t * DH + j], Bf[j * CHUNK + s], a);
    As[t * CHUNK + s] = a;
  }
  __syncthreads();
  #pragma unroll
  for (int l = 0; l < 4; ++l) {
    int idx = tid + l * 256;
    int r = idx >> 4, c4 = (idx & 15) << 2;
    size_t g = (size_t)(c * CHUNK + r) * D_DIM + hh * DH + c4;
    *(float4*)&Bf[r * DH + c4] = *(const float4*)(Km + g);
  }
  __syncthreads();
  const int i = tid & 63, tg = tid >> 6;
  float acc[16];
  #pragma unroll
  for (int rr = 0; rr < 16; ++rr) {
    int t = rr * 4 + tg;
    float o = 0.f;
    for (int s = 0; s <= t; ++s)
      o = fmaf(As[t * CHUNK + s], Bf[s * DH + i], o);
    acc[rr] = o;
  }
  __syncthreads();
  #pragma unroll
  for (int l = 0; l < 4; ++l) {
    int idx = tid + l * 256;
    int r = idx >> 4, c4 = (idx & 15) << 2;
    size_t g = ((size_t)c * H_DIM + hh) * 4096 + (size_t)r * DH + c4;
    float4 mv = *(const float4*)(M + g);
    Bf[(c4 + 0) * DH + r] = mv.x;
    Bf[(c4 + 1) * DH + r] = mv.y;
    Bf[(c4 + 2) * DH + r] = mv.z;
    Bf[(c4 + 3) * DH + r] = mv.w;
  }
  __syncthreads();
  const float gi = gamma[hh * DH + i];
  #pragma unroll
  for (int rr = 0; rr < 16; ++rr) {
    int t = rr * 4 + tg;
    float o = acc[rr];
    for (int j = 0; j < DH; ++j)
      o = fmaf(Qs[t * DH + j], Bf[j * DH + i], o);
    o = fmaf((float)(c * CHUNK + t + 1) * gi, Sq[t], o);
    O[(size_t)(c * CHUNK + t) * D_DIM + hh * DH + i] = o;
  }
}

// ------------------------------------------------------------- gated SiLU
__device__ inline float sigf(float x) { return 1.0f / (1.0f + expf(-x)); }

__global__ __launch_bounds__(256) void gate_act(
    const float* __restrict__ G, ushort* __restrict__ Mh,
    ushort* __restrict__ Ml) {
  const int n4 = T_DIM * (D_DIM / 4);
  for (int p = blockIdx.x * 256 + threadIdx.x; p < n4; p += gridDim.x * 256) {
    int t = p / (D_DIM / 4);
    int d = (p % (D_DIM / 4)) * 4;
    size_t gbase = (size_t)t * (2 * D_DIM) + d;
    float4 gv = *(const float4*)(G + gbase);
    float4 mv = *(const float4*)(G + gbase + D_DIM);
    float rr[4];
    rr[0] = mv.x * sigf(mv.x) * sigf(gv.x);
    rr[1] = mv.y * sigf(mv.y) * sigf(gv.y);
    rr[2] = mv.z * sigf(mv.z) * sigf(gv.z);
    rr[3] = mv.w * sigf(mv.w) * sigf(gv.w);
    ushort h[4], l[4];
    #pragma unroll
    for (int j = 0; j < 4; ++j) split2(rr[j], h[j], l[j]);
    size_t off = (size_t)t * D_DIM + d;
    *(ushort4*)(Mh + off) = make_ushort4(h[0], h[1], h[2], h[3]);
    *(ushort4*)(Ml + off) = make_ushort4(l[0], l[1], l[2], l[3]);
  }
}

// ---------------------------------------------------------------- launcher
// ws layout (5 * TD floats = 160 MB):
//   [0,TD):    ACT  split-bf16 act (XN -> X2) ; also S (fp32) between
//   [TD,2TD):  Q fp32            -> G low half
//   [2TD,3TD): Kb fp32           -> G high half
//   [3TD,4TD): Vb fp32           -> Min split-bf16
//   [4TD,5TD): WT split-bf16 (JIT per-weight transpose, reused 5x)
// O and Y live in d_out (every element written before read each launch).
extern "C" void kernel_launch(void* const* d_in, const int* in_sizes, int n_in,
                              void* d_out, int out_size, void* d_ws, size_t ws_size,
                              hipStream_t stream) {
  const float* x     = (const float*)d_in[0];
  const float* st0   = (const float*)d_in[1];
  const float* Wq    = (const float*)d_in[2];
  const float* Wk    = (const float*)d_in[3];
  const float* Wv    = (const float*)d_in[4];
  const float* gamma = (const float*)d_in[5];
  const float* Wgate = (const float*)d_in[6];
  const float* Wdown = (const float*)d_in[7];
  const float* ln1w  = (const float*)d_in[8];
  const float* ln1b  = (const float*)d_in[9];
  const float* ln2w  = (const float*)d_in[10];
  const float* ln2b  = (const float*)d_in[11];

  const size_t TD = (size_t)T_DIM * D_DIM;   // 8M elems
  if (ws_size < 5 * TD * sizeof(float)) return;  // clean, visible failure

  float* out    = (float*)d_out;
  float* fs_out = out + TD;

  float* ws = (float*)d_ws;
  ushort* ACTh = (ushort*)ws;            // TD ushorts
  ushort* ACTl = ACTh + TD;
  float*  Q    = ws + TD;
  float*  Kb   = ws + 2 * TD;
  float*  Vb   = ws + 3 * TD;
  ushort* WTh  = (ushort*)(ws + 4 * TD);
  ushort* WTl  = WTh + TD;
  float*  S    = ws;                     // reuses ACT (dead after QKV gemms)
  float*  G    = Q;                      // spans Q..Kb (2TD floats)
  ushort* Mh   = (ushort*)Vb;
  ushort* Ml   = Mh + TD;
  float*  O    = out;
  float*  Y    = out;

  dim3 blk(256);
  dim3 gQKV(D_DIM / BN, T_DIM / BM);         // 32 x 32 = 1024 blocks
  dim3 gGate(2 * D_DIM / BN, T_DIM / BM);    // 64 x 32 = 2048 blocks
  dim3 tsq(32, 32), tsg(64, 32);

  // LN1 -> split activations
  ln_fwd<<<T_DIM, blk, 0, stream>>>(x, nullptr, nullptr, ln1w, ln1b, ACTh, ACTl);

  // QKV GEMMs (JIT weight transpose+split each)
  tsplit<<<tsq, blk, 0, stream>>>(Wq, WTh, WTl, D_DIM, D_DIM);
  gemm_bf16s<<<gQKV, blk, 0, stream>>>(ACTh, ACTl, WTh, WTl, nullptr, Q,  T_DIM, D_DIM, D_DIM);
  tsplit<<<tsq, blk, 0, stream>>>(Wk, WTh, WTl, D_DIM, D_DIM);
  gemm_bf16s<<<gQKV, blk, 0, stream>>>(ACTh, ACTl, WTh, WTl, nullptr, Kb, T_DIM, D_DIM, D_DIM);
  tsplit<<<tsq, blk, 0, stream>>>(Wv, WTh, WTl, D_DIM, D_DIM);
  gemm_bf16s<<<gQKV, blk, 0, stream>>>(ACTh, ACTl, WTh, WTl, nullptr, Vb, T_DIM, D_DIM, D_DIM);

  // linear-attention path (fp32)
  chunk_kv_sums<<<dim3(NCHUNK, H_DIM), blk, 0, stream>>>(Kb, Vb, S);
  state_scan<<<dim3(16, H_DIM), blk, 0, stream>>>(st0, gamma, S, fs_out);
  attn_intra<<<dim3(NCHUNK, H_DIM), blk, 0, stream>>>(Q, Kb, Vb, S, gamma, O);

  // Y = x + O (in d_out), X2 = split-bf16 LN2(Y)
  ln_fwd<<<T_DIM, blk, 0, stream>>>(x, O, Y, ln2w, ln2b, ACTh, ACTl);

  // MLP
  tsplit<<<tsg, blk, 0, stream>>>(Wgate, WTh, WTl, D_DIM, 2 * D_DIM);
  gemm_bf16s<<<gGate, blk, 0, stream>>>(ACTh, ACTl, WTh, WTl, nullptr, G, T_DIM, 2 * D_DIM, D_DIM);
  gate_act<<<2048, blk, 0, stream>>>(G, Mh, Ml);
  tsplit<<<tsq, blk, 0, stream>>>(Wdown, WTh, WTl, D_DIM, D_DIM);
  // out = Min @ Wdown + Y (C aliases Add; same-offset read-before-write)
  gemm_bf16s<<<gQKV, blk, 0, stream>>>(Mh, Ml, WTh, WTl, Y, out, T_DIM, D_DIM, D_DIM);
}

// Round 7
// 1100.827 us; speedup vs baseline: 1.0957x; 1.0957x over previous
//
#include <hip/hip_runtime.h>

#define T_DIM 4096
#define D_DIM 2048
#define H_DIM 32
#define DH    64
#define CHUNK 64
#define NCHUNK (T_DIM / CHUNK)
#define EPS 1e-5f

typedef __attribute__((ext_vector_type(8))) short short8;
typedef __attribute__((ext_vector_type(4))) float f32x4;

// ----------------------------------------------------------- bf16 split utils
__device__ inline ushort f2bf(float f) {
  uint u = __float_as_uint(f);
  u += 0x7FFF + ((u >> 16) & 1);          // RNE
  return (ushort)(u >> 16);
}
__device__ inline float bf2f(ushort h) { return __uint_as_float(((uint)h) << 16); }
__device__ inline void split2(float f, ushort& hi, ushort& lo) {
  hi = f2bf(f);
  lo = f2bf(f - bf2f(hi));
}

// ------------------------------------------------------ global->LDS async DMA
// LDS dest = wave-uniform base + lane*16B (m97/m104-verified semantics).
__device__ __forceinline__ void gload16(const void* g, void* lds) {
  __builtin_amdgcn_global_load_lds(
      (const __attribute__((address_space(1))) unsigned int*)g,
      (__attribute__((address_space(3))) unsigned int*)lds, 16, 0, 0);
}

// ---------------------------------------------------------------- LN helper
__device__ inline void block_reduce_2(float& s1, float& s2) {
  __shared__ float red[8];
  #pragma unroll
  for (int off = 32; off > 0; off >>= 1) {
    s1 += __shfl_down(s1, off, 64);
    s2 += __shfl_down(s2, off, 64);
  }
  int lane = threadIdx.x & 63, wid = threadIdx.x >> 6;
  if (lane == 0) { red[wid] = s1; red[4 + wid] = s2; }
  __syncthreads();
  s1 = red[0] + red[1] + red[2] + red[3];
  s2 = red[4] + red[5] + red[6] + red[7];
}

// LN over rows of length D_DIM; emits SPLIT bf16 (hi, lo).
// If Add != nullptr: input = X + Add, pre-LN sum stored fp32 to Yout
// (Yout may alias Add: same-thread read-before-write at same offsets).
__global__ __launch_bounds__(256) void ln_fwd(
    const float* __restrict__ X, const float* Add, float* Yout,
    const float* __restrict__ w, const float* __restrict__ b,
    ushort* __restrict__ out_hi, ushort* __restrict__ out_lo) {
  const int row = blockIdx.x;
  const size_t base = (size_t)row * D_DIM;
  const int t = threadIdx.x;

  float4 v0 = *(const float4*)(X + base + (size_t)t * 4);
  float4 v1 = *(const float4*)(X + base + (size_t)(t + 256) * 4);
  if (Add) {
    float4 a0 = *(const float4*)(Add + base + (size_t)t * 4);
    float4 a1 = *(const float4*)(Add + base + (size_t)(t + 256) * 4);
    v0.x += a0.x; v0.y += a0.y; v0.z += a0.z; v0.w += a0.w;
    v1.x += a1.x; v1.y += a1.y; v1.z += a1.z; v1.w += a1.w;
    *(float4*)(Yout + base + (size_t)t * 4) = v0;
    *(float4*)(Yout + base + (size_t)(t + 256) * 4) = v1;
  }
  float s  = v0.x + v0.y + v0.z + v0.w + v1.x + v1.y + v1.z + v1.w;
  float ss = v0.x*v0.x + v0.y*v0.y + v0.z*v0.z + v0.w*v0.w
           + v1.x*v1.x + v1.y*v1.y + v1.z*v1.z + v1.w*v1.w;
  block_reduce_2(s, ss);
  const float m   = s * (1.0f / D_DIM);
  const float var = ss * (1.0f / D_DIM) - m * m;
  const float r   = rsqrtf(var + EPS);

  float4 w0 = *(const float4*)(w + (size_t)t * 4);
  float4 w1 = *(const float4*)(w + (size_t)(t + 256) * 4);
  float4 b0 = *(const float4*)(b + (size_t)t * 4);
  float4 b1 = *(const float4*)(b + (size_t)(t + 256) * 4);
  float o[8];
  o[0] = (v0.x - m) * r * w0.x + b0.x;
  o[1] = (v0.y - m) * r * w0.y + b0.y;
  o[2] = (v0.z - m) * r * w0.z + b0.z;
  o[3] = (v0.w - m) * r * w0.w + b0.w;
  o[4] = (v1.x - m) * r * w1.x + b1.x;
  o[5] = (v1.y - m) * r * w1.y + b1.y;
  o[6] = (v1.z - m) * r * w1.z + b1.z;
  o[7] = (v1.w - m) * r * w1.w + b1.w;
  ushort h[8], l[8];
  #pragma unroll
  for (int j = 0; j < 8; ++j) split2(o[j], h[j], l[j]);
  *(ushort4*)(out_hi + base + (size_t)t * 4) = make_ushort4(h[0], h[1], h[2], h[3]);
  *(ushort4*)(out_lo + base + (size_t)t * 4) = make_ushort4(l[0], l[1], l[2], l[3]);
  *(ushort4*)(out_hi + base + (size_t)(t + 256) * 4) = make_ushort4(h[4], h[5], h[6], h[7]);
  *(ushort4*)(out_lo + base + (size_t)(t + 256) * 4) = make_ushort4(l[4], l[5], l[6], l[7]);
}

// ----------------------------------- weight transpose + bf16 split (JIT, 64x64)
// W [KR][NC] fp32 -> WT_hi/WT_lo [NC][KR] bf16
__global__ __launch_bounds__(256) void tsplit(
    const float* __restrict__ W, ushort* __restrict__ WTh,
    ushort* __restrict__ WTl, int KR, int NC) {
  __shared__ float tile[64][65];
  const int t = threadIdx.x;
  const int k0 = blockIdx.y * 64, n0 = blockIdx.x * 64;
  #pragma unroll
  for (int p = 0; p < 4; ++p) {
    int r = (t >> 4) + p * 16;
    int c = (t & 15) * 4;
    *(float4*)&tile[r][c] = *(const float4*)&W[(size_t)(k0 + r) * NC + n0 + c];
  }
  __syncthreads();
  #pragma unroll
  for (int p = 0; p < 4; ++p) {
    int n = (t >> 4) + p * 16;
    int c = (t & 15) * 4;
    ushort h[4], l[4];
    #pragma unroll
    for (int j = 0; j < 4; ++j) split2(tile[c + j][n], h[j], l[j]);
    size_t off = (size_t)(n0 + n) * KR + k0 + c;
    *(ushort4*)(WTh + off) = make_ushort4(h[0], h[1], h[2], h[3]);
    *(ushort4*)(WTl + off) = make_ushort4(l[0], l[1], l[2], l[3]);
  }
}

// ------------------------------------------- split-bf16 MFMA GEMM (3 products)
// A as hi/lo bf16 [M][K] (lda=K), B as TRANSPOSED hi/lo bf16 [N][K] (ldb=K).
// Columns [0,Nq) -> Cq (ld ldq); columns [Nq,N) -> Cv (ld ldv), col-Nq offset.
// Split-K: blockIdx.z computes K-range [z*Klen,(z+1)*Klen) into Cq + z*zstride.
// 128x128 tile, 4 waves (64x64 each), BK=32, global_load_lds staging, linear
// LDS + both-sides k-quarter XOR swizzle (round-5-verified: 0 conflicts).
// XCD slab ordering: xcd = hwid&7 owns a bx-slab of GX/8 N-tiles; within the
// slab bx-minor / by-major -> B-slab (~2-3MB) stays L2-resident, A reused.
#define BM 128
#define BN 128
#define BK 32
__global__ __launch_bounds__(256) void gemm_bf16s(
    const ushort* __restrict__ Ah, const ushort* __restrict__ Al,
    const ushort* __restrict__ Bh, const ushort* __restrict__ Bl,
    float* __restrict__ Cq, float* __restrict__ Cv,
    int Nq, int ldq, int ldv, size_t zstride, int K, int Klen) {
  __shared__ ushort Ash[BM * BK];   // 8KB
  __shared__ ushort Asl[BM * BK];   // 8KB
  __shared__ ushort Bsh[BN * BK];   // 8KB
  __shared__ ushort Bsl[BN * BK];   // 8KB  (32KB total)
  const int tid = threadIdx.x;

  // XCD slab swizzle (bijective when GX%8==0; true for all our grids)
  int bx, by, bz;
  {
    const int GX = gridDim.x, GY = gridDim.y;
    const int hwid = ((int)blockIdx.z * GY + (int)blockIdx.y) * GX + (int)blockIdx.x;
    const int BXC = GX >> 3;
    const int xcd = hwid & 7, s = hwid >> 3;
    const int bxl = s % BXC;
    const int t2 = s / BXC;
    by = t2 % GY;
    bz = t2 / GY;
    bx = xcd * BXC + bxl;
  }
  const int bm = by * BM, bn = bx * BN;
  const int koff = bz * Klen;

  const int l = tid & 63, wv = tid >> 6;
  const int lrow = l >> 2;                       // staging row within 16-row chunk
  const int q = (l & 3) ^ ((l >> 3) & 3);        // pre-swizzled global k-quarter
  const int ln = l & 15, kg = l >> 4;
  const int xs = (kg ^ ((ln >> 1) & 3)) * 8;     // swizzled frag slot (ushorts)
  const int wm_ = (wv >> 1) * 64, wn_ = (wv & 1) * 64;

  f32x4 acc[4][4];
  #pragma unroll
  for (int i = 0; i < 4; ++i)
    #pragma unroll
    for (int j = 0; j < 4; ++j) {
      f32x4 z = {0.f, 0.f, 0.f, 0.f};
      acc[i][j] = z;
    }

  for (int k0 = koff; k0 < koff + Klen; k0 += BK) {
    // stage: 8 global_load_lds_dwordx4 per wave (A 4, B 4)
    {
      size_t ga = (size_t)(bm + wv * 32 + lrow) * K + k0 + q * 8;
      gload16(Ah + ga,                  &Ash[(wv * 32) * BK]);
      gload16(Ah + ga + 16 * (size_t)K, &Ash[(wv * 32 + 16) * BK]);
      gload16(Al + ga,                  &Asl[(wv * 32) * BK]);
      gload16(Al + ga + 16 * (size_t)K, &Asl[(wv * 32 + 16) * BK]);
      size_t gb = (size_t)(bn + wv * 32 + lrow) * K + k0 + q * 8;
      gload16(Bh + gb,                  &Bsh[(wv * 32) * BK]);
      gload16(Bh + gb + 16 * (size_t)K, &Bsh[(wv * 32 + 16) * BK]);
      gload16(Bl + gb,                  &Bsl[(wv * 32) * BK]);
      gload16(Bl + gb + 16 * (size_t)K, &Bsl[(wv * 32 + 16) * BK]);
    }
    __syncthreads();   // compiler drains vmcnt(0) before s_barrier

    short8 fah[4], fal[4], fbh[4], fbl[4];
    #pragma unroll
    for (int i = 0; i < 4; ++i) {
      fah[i] = *(const short8*)&Ash[(wm_ + i * 16 + ln) * BK + xs];
      fal[i] = *(const short8*)&Asl[(wm_ + i * 16 + ln) * BK + xs];
      fbh[i] = *(const short8*)&Bsh[(wn_ + i * 16 + ln) * BK + xs];
      fbl[i] = *(const short8*)&Bsl[(wn_ + i * 16 + ln) * BK + xs];
    }
    #pragma unroll
    for (int i = 0; i < 4; ++i)
      #pragma unroll
      for (int j = 0; j < 4; ++j) {
        acc[i][j] = __builtin_amdgcn_mfma_f32_16x16x32_bf16(fah[i], fbh[j], acc[i][j], 0, 0, 0);
        acc[i][j] = __builtin_amdgcn_mfma_f32_16x16x32_bf16(fah[i], fbl[j], acc[i][j], 0, 0, 0);
        acc[i][j] = __builtin_amdgcn_mfma_f32_16x16x32_bf16(fal[i], fbh[j], acc[i][j], 0, 0, 0);
      }
    __syncthreads();
  }

  // epilogue: dual destination (block-uniform branch since BN | Nq)
  float* Cp;
  int ldc, cb;
  if (bn < Nq) { Cp = Cq + bz * zstride; ldc = ldq; cb = bn; }
  else         { Cp = Cv;                ldc = ldv; cb = bn - Nq; }
  #pragma unroll
  for (int i = 0; i < 4; ++i)
    #pragma unroll
    for (int j = 0; j < 4; ++j)
      #pragma unroll
      for (int rg = 0; rg < 4; ++rg) {
        int row = bm + wm_ + i * 16 + kg * 4 + rg;
        int col = cb + wn_ + j * 16 + ln;
        Cp[(size_t)row * ldc + col] = acc[i][j][rg];
      }
}

// --------------------------------------------- split-K reduce: out += p0 + p1
__global__ __launch_bounds__(256) void redadd(
    const float* __restrict__ p0, const float* __restrict__ p1,
    float* __restrict__ out) {
  const int n4 = T_DIM * (D_DIM / 4);
  for (int p = blockIdx.x * 256 + threadIdx.x; p < n4; p += gridDim.x * 256) {
    size_t i = (size_t)p * 4;
    float4 a = *(const float4*)(p0 + i);
    float4 b = *(const float4*)(p1 + i);
    float4 c = *(const float4*)(out + i);
    c.x += a.x + b.x; c.y += a.y + b.y; c.z += a.z + b.z; c.w += a.w + b.w;
    *(float4*)(out + i) = c;
  }
}

// ------------------------------------------------- per-chunk  sum k_s (x) v_s
__global__ __launch_bounds__(256) void chunk_kv_sums(
    const float* __restrict__ Km, int ldk,
    const float* __restrict__ Vm, int ldv, float* __restrict__ S) {
  __shared__ float Ks[CHUNK][DH];
  __shared__ float Vs[CHUNK][DH];
  const int c = blockIdx.x, hh = blockIdx.y, tid = threadIdx.x;
  #pragma unroll
  for (int l = 0; l < 4; ++l) {
    int idx = tid + l * 256;
    int s = idx >> 4, c4 = (idx & 15) << 2;
    *(float4*)&Ks[s][c4] = *(const float4*)(Km + (size_t)(c * CHUNK + s) * ldk + hh * DH + c4);
    *(float4*)&Vs[s][c4] = *(const float4*)(Vm + (size_t)(c * CHUNK + s) * ldv + hh * DH + c4);
  }
  __syncthreads();
  const int i0 = (tid >> 4) << 2;
  const int j0 = (tid & 15) << 2;
  float acc[4][4] = {};
  for (int s = 0; s < CHUNK; ++s) {
    float kv[4], vv[4];
    *(float4*)kv = *(const float4*)&Ks[s][i0];
    *(float4*)vv = *(const float4*)&Vs[s][j0];
    #pragma unroll
    for (int ii = 0; ii < 4; ++ii)
      #pragma unroll
      for (int jj = 0; jj < 4; ++jj)
        acc[ii][jj] = fmaf(kv[ii], vv[jj], acc[ii][jj]);
  }
  const size_t base = ((size_t)c * H_DIM + hh) * (DH * DH);
  #pragma unroll
  for (int ii = 0; ii < 4; ++ii)
    *(float4*)&S[base + (size_t)(i0 + ii) * DH + j0] =
        make_float4(acc[ii][0], acc[ii][1], acc[ii][2], acc[ii][3]);
}

// --------------------------- exclusive prefix over chunks (in place) + final
__global__ __launch_bounds__(256) void state_scan(
    const float* __restrict__ st0, const float* __restrict__ gamma,
    float* __restrict__ S, float* __restrict__ fs_out) {
  const int hh = blockIdx.y;
  const int e = blockIdx.x * 256 + threadIdx.x;
  float run = st0[(size_t)hh * 4096 + e];
  for (int c = 0; c < NCHUNK; ++c) {
    size_t idx = ((size_t)c * H_DIM + hh) * 4096 + e;
    float tmp = S[idx];
    S[idx] = run;
    run += tmp;
  }
  const int i = e >> 6;
  fs_out[(size_t)hh * 4096 + e] = run + (float)T_DIM * gamma[hh * DH + i];
}

// ------------------------------------------------------- per-chunk attention
// O may alias Vm (in-place): block (c,h) fully reads its V tile into LDS
// before writing O, and no other block touches that tile.
__global__ __launch_bounds__(256) void attn_intra(
    const float* __restrict__ Qm, int ldq,
    const float* __restrict__ Km, int ldk,
    const float* Vm, int ldv,
    const float* __restrict__ M, const float* __restrict__ gamma,
    float* O, int ldo) {
  __shared__ float Qs[CHUNK * DH];
  __shared__ float Bf[CHUNK * DH];
  __shared__ float As[CHUNK * CHUNK];
  __shared__ float Sq[CHUNK];
  const int c = blockIdx.x, hh = blockIdx.y, tid = threadIdx.x;

  #pragma unroll
  for (int l = 0; l < 4; ++l) {
    int idx = tid + l * 256;
    int r = idx >> 4, c4 = (idx & 15) << 2;
    *(float4*)&Qs[r * DH + c4] = *(const float4*)(Qm + (size_t)(c * CHUNK + r) * ldq + hh * DH + c4);
    float4 vv = *(const float4*)(Vm + (size_t)(c * CHUNK + r) * ldv + hh * DH + c4);
    Bf[(c4 + 0) * CHUNK + r] = vv.x;
    Bf[(c4 + 1) * CHUNK + r] = vv.y;
    Bf[(c4 + 2) * CHUNK + r] = vv.z;
    Bf[(c4 + 3) * CHUNK + r] = vv.w;
  }
  __syncthreads();
  if (tid < CHUNK) {
    float s = 0.f;
    for (int j = 0; j < DH; ++j) s += Qs[tid * DH + j];
    Sq[tid] = s;
  }
  #pragma unroll
  for (int rr = 0; rr < 16; ++rr) {
    int p = tid + rr * 256;
    int t = p >> 6, s = p & 63;
    float a = 0.f;
    for (int j = 0; j < DH; ++j)
      a = fmaf(Qs[t * DH + j], Bf[j * CHUNK + s], a);
    As[t * CHUNK + s] = a;
  }
  __syncthreads();
  #pragma unroll
  for (int l = 0; l < 4; ++l) {
    int idx = tid + l * 256;
    int r = idx >> 4, c4 = (idx & 15) << 2;
    *(float4*)&Bf[r * DH + c4] = *(const float4*)(Km + (size_t)(c * CHUNK + r) * ldk + hh * DH + c4);
  }
  __syncthreads();
  const int i = tid & 63, tg = tid >> 6;
  float acc[16];
  #pragma unroll
  for (int rr = 0; rr < 16; ++rr) {
    int t = rr * 4 + tg;
    float o = 0.f;
    for (int s = 0; s <= t; ++s)
      o = fmaf(As[t * CHUNK + s], Bf[s * DH + i], o);
    acc[rr] = o;
  }
  __syncthreads();
  #pragma unroll
  for (int l = 0; l < 4; ++l) {
    int idx = tid + l * 256;
    int r = idx >> 4, c4 = (idx & 15) << 2;
    size_t g = ((size_t)c * H_DIM + hh) * 4096 + (size_t)r * DH + c4;
    float4 mv = *(const float4*)(M + g);
    Bf[(c4 + 0) * DH + r] = mv.x;
    Bf[(c4 + 1) * DH + r] = mv.y;
    Bf[(c4 + 2) * DH + r] = mv.z;
    Bf[(c4 + 3) * DH + r] = mv.w;
  }
  __syncthreads();
  const float gi = gamma[hh * DH + i];
  #pragma unroll
  for (int rr = 0; rr < 16; ++rr) {
    int t = rr * 4 + tg;
    float o = acc[rr];
    for (int j = 0; j < DH; ++j)
      o = fmaf(Qs[t * DH + j], Bf[j * DH + i], o);
    o = fmaf((float)(c * CHUNK + t + 1) * gi, Sq[t], o);
    O[(size_t)(c * CHUNK + t) * ldo + hh * DH + i] = o;
  }
}

// ------------------------------------------------------------- gated SiLU
__device__ inline float sigf(float x) { return 1.0f / (1.0f + expf(-x)); }

__global__ __launch_bounds__(256) void gate_act(
    const float* __restrict__ G, ushort* __restrict__ Mh,
    ushort* __restrict__ Ml) {
  const int n4 = T_DIM * (D_DIM / 4);
  for (int p = blockIdx.x * 256 + threadIdx.x; p < n4; p += gridDim.x * 256) {
    int t = p / (D_DIM / 4);
    int d = (p % (D_DIM / 4)) * 4;
    size_t gbase = (size_t)t * (2 * D_DIM) + d;
    float4 gv = *(const float4*)(G + gbase);
    float4 mv = *(const float4*)(G + gbase + D_DIM);
    float rr[4];
    rr[0] = mv.x * sigf(mv.x) * sigf(gv.x);
    rr[1] = mv.y * sigf(mv.y) * sigf(gv.y);
    rr[2] = mv.z * sigf(mv.z) * sigf(gv.z);
    rr[3] = mv.w * sigf(mv.w) * sigf(gv.w);
    ushort h[4], l[4];
    #pragma unroll
    for (int j = 0; j < 4; ++j) split2(rr[j], h[j], l[j]);
    size_t off = (size_t)t * D_DIM + d;
    *(ushort4*)(Mh + off) = make_ushort4(h[0], h[1], h[2], h[3]);
    *(ushort4*)(Ml + off) = make_ushort4(l[0], l[1], l[2], l[3]);
  }
}

// ---------------------------------------------------------------- launcher
// TD = T*D = 8.39M elems, NK = D*D = 4.19M.  ws layout (4.5*TD floats = 144MB):
//   region0 [0,TD):      ACTh/ACTl (TD ush each) -> S (TD fp32) -> Mh/Ml
//   region1 [TD,2TD):    QK cols 0..2047 | G low | split-K partial P0
//   region2 [2TD,3TD):   QK cols 2048..4095 | G high | partial P1
//   region3 [3TD,4.5TD): WT hi|lo (QKV: 3NK+3NK ush = exactly 1.5TD floats)
// d_out[0,TD): V -> O -> Y -> final out.  fs_out at d_out[TD,..).
extern "C" void kernel_launch(void* const* d_in, const int* in_sizes, int n_in,
                              void* d_out, int out_size, void* d_ws, size_t ws_size,
                              hipStream_t stream) {
  const float* x     = (const float*)d_in[0];
  const float* st0   = (const float*)d_in[1];
  const float* Wq    = (const float*)d_in[2];
  const float* Wk    = (const float*)d_in[3];
  const float* Wv    = (const float*)d_in[4];
  const float* gamma = (const float*)d_in[5];
  const float* Wgate = (const float*)d_in[6];
  const float* Wdown = (const float*)d_in[7];
  const float* ln1w  = (const float*)d_in[8];
  const float* ln1b  = (const float*)d_in[9];
  const float* ln2w  = (const float*)d_in[10];
  const float* ln2b  = (const float*)d_in[11];

  const size_t TD = (size_t)T_DIM * D_DIM;
  const size_t NK = (size_t)D_DIM * D_DIM;
  if (ws_size < (TD * 9) / 2 * sizeof(float)) return;  // 4.5*TD guard

  float* out    = (float*)d_out;
  float* fs_out = out + TD;

  float* ws = (float*)d_ws;
  ushort* ACTh = (ushort*)ws;                  // region0
  ushort* ACTl = ACTh + TD;
  float*  S    = ws;                           // region0 (after QKV)
  ushort* Mh   = (ushort*)ws;                  // region0 (after gate_act)
  ushort* Ml   = Mh + TD;
  float*  QK   = ws + TD;                      // regions1+2: [T][4096]
  float*  G    = ws + TD;                      // regions1+2: [T][4096]
  float*  P0   = ws + TD;                      // split-K partials
  float*  P1   = ws + 2 * TD;
  ushort* WTh  = (ushort*)(ws + 3 * TD);       // region3
  float*  V    = out;                          // d_out[0,TD): V -> O -> Y
  float*  O    = out;
  float*  Y    = out;

  dim3 blk(256);
  dim3 tsq(32, 32);

  // ---- LN1 -> split activations
  ln_fwd<<<T_DIM, blk, 0, stream>>>(x, nullptr, nullptr, ln1w, ln1b, ACTh, ACTl);

  // ---- fused QKV GEMM: WT = [Wq^T; Wk^T; Wv^T], N = 6144
  {
    ushort* WTl3 = WTh + 3 * NK;               // lo starts after 3NK hi
    tsplit<<<tsq, blk, 0, stream>>>(Wq, WTh,          WTl3,          D_DIM, D_DIM);
    tsplit<<<tsq, blk, 0, stream>>>(Wk, WTh + NK,     WTl3 + NK,     D_DIM, D_DIM);
    tsplit<<<tsq, blk, 0, stream>>>(Wv, WTh + 2 * NK, WTl3 + 2 * NK, D_DIM, D_DIM);
    // cols [0,4096) -> QK (ld 4096); cols [4096,6144) -> V in d_out (ld 2048)
    gemm_bf16s<<<dim3(48, 32, 1), blk, 0, stream>>>(
        ACTh, ACTl, WTh, WTl3, QK, V, 2 * D_DIM, 2 * D_DIM, D_DIM,
        0, D_DIM, D_DIM);
  }

  // ---- linear-attention path (fp32); K at QK cols [2048,4096)
  chunk_kv_sums<<<dim3(NCHUNK, H_DIM), blk, 0, stream>>>(
      QK + D_DIM, 2 * D_DIM, V, D_DIM, S);
  state_scan<<<dim3(16, H_DIM), blk, 0, stream>>>(st0, gamma, S, fs_out);
  attn_intra<<<dim3(NCHUNK, H_DIM), blk, 0, stream>>>(
      QK, 2 * D_DIM, QK + D_DIM, 2 * D_DIM, V, D_DIM, S, gamma, O, D_DIM);

  // ---- Y = x + O (in d_out), ACT = split-bf16 LN2(Y)
  ln_fwd<<<T_DIM, blk, 0, stream>>>(x, O, Y, ln2w, ln2b, ACTh, ACTl);

  // ---- MLP gate GEMM: N = 4096 -> G (regions1+2)
  {
    ushort* WThg = WTh;                        // [0,2NK) hi
    ushort* WTlg = WTh + 2 * NK;               // [2NK,4NK) lo
    tsplit<<<dim3(64, 32), blk, 0, stream>>>(Wgate, WThg, WTlg, D_DIM, 2 * D_DIM);
    gemm_bf16s<<<dim3(32, 32, 1), blk, 0, stream>>>(
        ACTh, ACTl, WThg, WTlg, G, nullptr, 2 * D_DIM, 2 * D_DIM, 0,
        0, D_DIM, D_DIM);
  }
  gate_act<<<2048, blk, 0, stream>>>(G, Mh, Ml);

  // ---- Wdown split-K=2 -> P0,P1; then out = Y + P0 + P1
  {
    ushort* WThd = WTh;
    ushort* WTld = WTh + NK;
    tsplit<<<tsq, blk, 0, stream>>>(Wdown, WThd, WTld, D_DIM, D_DIM);
    gemm_bf16s<<<dim3(16, 32, 2), blk, 0, stream>>>(
        Mh, Ml, WThd, WTld, P0, nullptr, D_DIM, D_DIM, 0,
        TD, D_DIM, D_DIM / 2);
    redadd<<<2048, blk, 0, stream>>>(P0, P1, out);
  }
}

// Round 8
// 912.707 us; speedup vs baseline: 1.3216x; 1.2061x over previous
//
#include <hip/hip_runtime.h>

#define T_DIM 4096
#define D_DIM 2048
#define H_DIM 32
#define DH    64
#define CHUNK 64
#define NCHUNK (T_DIM / CHUNK)
#define EPS 1e-5f

typedef __attribute__((ext_vector_type(8))) short short8;
typedef __attribute__((ext_vector_type(4))) float f32x4;

// ----------------------------------------------------------- bf16 split utils
__device__ inline ushort f2bf(float f) {
  uint u = __float_as_uint(f);
  u += 0x7FFF + ((u >> 16) & 1);          // RNE
  return (ushort)(u >> 16);
}
__device__ inline float bf2f(ushort h) { return __uint_as_float(((uint)h) << 16); }
__device__ inline void split2(float f, ushort& hi, ushort& lo) {
  hi = f2bf(f);
  lo = f2bf(f - bf2f(hi));
}

// ------------------------------------------------------ global->LDS async DMA
__device__ __forceinline__ void gload16(const void* g, void* lds) {
  __builtin_amdgcn_global_load_lds(
      (const __attribute__((address_space(1))) unsigned int*)g,
      (__attribute__((address_space(3))) unsigned int*)lds, 16, 0, 0);
}

// ---------------------------------------------------------------- LN helper
__device__ inline void block_reduce_2(float& s1, float& s2) {
  __shared__ float red[8];
  #pragma unroll
  for (int off = 32; off > 0; off >>= 1) {
    s1 += __shfl_down(s1, off, 64);
    s2 += __shfl_down(s2, off, 64);
  }
  int lane = threadIdx.x & 63, wid = threadIdx.x >> 6;
  if (lane == 0) { red[wid] = s1; red[4 + wid] = s2; }
  __syncthreads();
  s1 = red[0] + red[1] + red[2] + red[3];
  s2 = red[4] + red[5] + red[6] + red[7];
}

// LN over rows of length D_DIM; emits bf16 hi (and lo if out_lo != null).
// If Add != nullptr: input = X + Add, pre-LN sum stored fp32 to Yout
// (Yout may alias Add: same-thread read-before-write at same offsets).
__global__ __launch_bounds__(256) void ln_fwd(
    const float* __restrict__ X, const float* Add, float* Yout,
    const float* __restrict__ w, const float* __restrict__ b,
    ushort* __restrict__ out_hi, ushort* out_lo) {
  const int row = blockIdx.x;
  const size_t base = (size_t)row * D_DIM;
  const int t = threadIdx.x;

  float4 v0 = *(const float4*)(X + base + (size_t)t * 4);
  float4 v1 = *(const float4*)(X + base + (size_t)(t + 256) * 4);
  if (Add) {
    float4 a0 = *(const float4*)(Add + base + (size_t)t * 4);
    float4 a1 = *(const float4*)(Add + base + (size_t)(t + 256) * 4);
    v0.x += a0.x; v0.y += a0.y; v0.z += a0.z; v0.w += a0.w;
    v1.x += a1.x; v1.y += a1.y; v1.z += a1.z; v1.w += a1.w;
    *(float4*)(Yout + base + (size_t)t * 4) = v0;
    *(float4*)(Yout + base + (size_t)(t + 256) * 4) = v1;
  }
  float s  = v0.x + v0.y + v0.z + v0.w + v1.x + v1.y + v1.z + v1.w;
  float ss = v0.x*v0.x + v0.y*v0.y + v0.z*v0.z + v0.w*v0.w
           + v1.x*v1.x + v1.y*v1.y + v1.z*v1.z + v1.w*v1.w;
  block_reduce_2(s, ss);
  const float m   = s * (1.0f / D_DIM);
  const float var = ss * (1.0f / D_DIM) - m * m;
  const float r   = rsqrtf(var + EPS);

  float4 w0 = *(const float4*)(w + (size_t)t * 4);
  float4 w1 = *(const float4*)(w + (size_t)(t + 256) * 4);
  float4 b0 = *(const float4*)(b + (size_t)t * 4);
  float4 b1 = *(const float4*)(b + (size_t)(t + 256) * 4);
  float o[8];
  o[0] = (v0.x - m) * r * w0.x + b0.x;
  o[1] = (v0.y - m) * r * w0.y + b0.y;
  o[2] = (v0.z - m) * r * w0.z + b0.z;
  o[3] = (v0.w - m) * r * w0.w + b0.w;
  o[4] = (v1.x - m) * r * w1.x + b1.x;
  o[5] = (v1.y - m) * r * w1.y + b1.y;
  o[6] = (v1.z - m) * r * w1.z + b1.z;
  o[7] = (v1.w - m) * r * w1.w + b1.w;
  if (out_lo) {
    ushort h[8], l[8];
    #pragma unroll
    for (int j = 0; j < 8; ++j) split2(o[j], h[j], l[j]);
    *(ushort4*)(out_hi + base + (size_t)t * 4) = make_ushort4(h[0], h[1], h[2], h[3]);
    *(ushort4*)(out_lo + base + (size_t)t * 4) = make_ushort4(l[0], l[1], l[2], l[3]);
    *(ushort4*)(out_hi + base + (size_t)(t + 256) * 4) = make_ushort4(h[4], h[5], h[6], h[7]);
    *(ushort4*)(out_lo + base + (size_t)(t + 256) * 4) = make_ushort4(l[4], l[5], l[6], l[7]);
  } else {
    ushort h[8];
    #pragma unroll
    for (int j = 0; j < 8; ++j) h[j] = f2bf(o[j]);
    *(ushort4*)(out_hi + base + (size_t)t * 4) = make_ushort4(h[0], h[1], h[2], h[3]);
    *(ushort4*)(out_hi + base + (size_t)(t + 256) * 4) = make_ushort4(h[4], h[5], h[6], h[7]);
  }
}

// ----------------------------------- weight transpose + bf16 split (JIT, 64x64)
// W [KR][NC] fp32 -> WT_hi (and WT_lo if non-null) [NC][KR] bf16
__global__ __launch_bounds__(256) void tsplit(
    const float* __restrict__ W, ushort* __restrict__ WTh,
    ushort* WTl, int KR, int NC) {
  __shared__ float tile[64][65];
  const int t = threadIdx.x;
  const int k0 = blockIdx.y * 64, n0 = blockIdx.x * 64;
  #pragma unroll
  for (int p = 0; p < 4; ++p) {
    int r = (t >> 4) + p * 16;
    int c = (t & 15) * 4;
    *(float4*)&tile[r][c] = *(const float4*)&W[(size_t)(k0 + r) * NC + n0 + c];
  }
  __syncthreads();
  #pragma unroll
  for (int p = 0; p < 4; ++p) {
    int n = (t >> 4) + p * 16;
    int c = (t & 15) * 4;
    size_t off = (size_t)(n0 + n) * KR + k0 + c;
    if (WTl) {
      ushort h[4], l[4];
      #pragma unroll
      for (int j = 0; j < 4; ++j) split2(tile[c + j][n], h[j], l[j]);
      *(ushort4*)(WTh + off) = make_ushort4(h[0], h[1], h[2], h[3]);
      *(ushort4*)(WTl + off) = make_ushort4(l[0], l[1], l[2], l[3]);
    } else {
      ushort h[4];
      #pragma unroll
      for (int j = 0; j < 4; ++j) h[j] = f2bf(tile[c + j][n]);
      *(ushort4*)(WTh + off) = make_ushort4(h[0], h[1], h[2], h[3]);
    }
  }
}

// --------------------- split-bf16 MFMA GEMM, 2-phase double-buffered pipeline
// NPROD=3: hi*hi + hi*lo + lo*hi (split numerics). NPROD=1: plain bf16.
// A [M][K] (lda=K), B TRANSPOSED [N][K] (ldb=K).
// Cols [0,Nq) -> Cq (ld ldq); cols [Nq,N) -> Cv (ld ldv).
// Split-K via blockIdx.z -> Cq + z*zstride.
// T3-min schedule: STAGE(buf^1, next) issued BEFORE ds_read+MFMA of buf;
// single __syncthreads() per K-step (drains vmcnt+lgkm, protects both bufs).
#define BM 128
#define BN 128
#define BK 32
template <int NPROD>
__global__ __launch_bounds__(256) void gemm_bf16s(
    const ushort* __restrict__ Ah, const ushort* __restrict__ Al,
    const ushort* __restrict__ Bh, const ushort* __restrict__ Bl,
    float* __restrict__ Cq, float* __restrict__ Cv,
    int Nq, int ldq, int ldv, size_t zstride, int K, int Klen) {
  __shared__ ushort Ash[2][BM * BK];                       // 2 x 8KB
  __shared__ ushort Bsh[2][BN * BK];                       // 2 x 8KB
  __shared__ ushort Asl[NPROD == 3 ? 2 : 1][NPROD == 3 ? BM * BK : 16];
  __shared__ ushort Bsl[NPROD == 3 ? 2 : 1][NPROD == 3 ? BN * BK : 16];
  const int tid = threadIdx.x;

  // XCD slab swizzle (bijective when GX%8==0; true for all our grids)
  int bx, by, bz;
  {
    const int GX = gridDim.x, GY = gridDim.y;
    const int hwid = ((int)blockIdx.z * GY + (int)blockIdx.y) * GX + (int)blockIdx.x;
    const int BXC = GX >> 3;
    const int xcd = hwid & 7, s = hwid >> 3;
    const int bxl = s % BXC;
    const int t2 = s / BXC;
    by = t2 % GY;
    bz = t2 / GY;
    bx = xcd * BXC + bxl;
  }
  const int bm = by * BM, bn = bx * BN;
  const int koff = bz * Klen, kend = koff + Klen;

  const int l = tid & 63, wv = tid >> 6;
  const int lrow = l >> 2;                       // staging row within 16-row chunk
  const int q = (l & 3) ^ ((l >> 3) & 3);        // pre-swizzled global k-quarter
  const int ln = l & 15, kg = l >> 4;
  const int xs = (kg ^ ((ln >> 1) & 3)) * 8;     // swizzled frag slot (ushorts)
  const int wm_ = (wv >> 1) * 64, wn_ = (wv & 1) * 64;

  auto STAGE = [&](int buf, int k0) {
    size_t ga = (size_t)(bm + wv * 32 + lrow) * K + k0 + q * 8;
    gload16(Ah + ga,                  &Ash[buf][(wv * 32) * BK]);
    gload16(Ah + ga + 16 * (size_t)K, &Ash[buf][(wv * 32 + 16) * BK]);
    size_t gb = (size_t)(bn + wv * 32 + lrow) * K + k0 + q * 8;
    gload16(Bh + gb,                  &Bsh[buf][(wv * 32) * BK]);
    gload16(Bh + gb + 16 * (size_t)K, &Bsh[buf][(wv * 32 + 16) * BK]);
    if constexpr (NPROD == 3) {
      gload16(Al + ga,                  &Asl[buf][(wv * 32) * BK]);
      gload16(Al + ga + 16 * (size_t)K, &Asl[buf][(wv * 32 + 16) * BK]);
      gload16(Bl + gb,                  &Bsl[buf][(wv * 32) * BK]);
      gload16(Bl + gb + 16 * (size_t)K, &Bsl[buf][(wv * 32 + 16) * BK]);
    }
  };

  f32x4 acc[4][4];
  #pragma unroll
  for (int i = 0; i < 4; ++i)
    #pragma unroll
    for (int j = 0; j < 4; ++j) {
      f32x4 z = {0.f, 0.f, 0.f, 0.f};
      acc[i][j] = z;
    }

  STAGE(0, koff);
  __syncthreads();
  int cur = 0;
  for (int k0 = koff; k0 < kend; k0 += BK) {
    if (k0 + BK < kend) STAGE(cur ^ 1, k0 + BK);   // loads fly during MFMA

    short8 fah[4], fbh[4];
    #pragma unroll
    for (int i = 0; i < 4; ++i) {
      fah[i] = *(const short8*)&Ash[cur][(wm_ + i * 16 + ln) * BK + xs];
      fbh[i] = *(const short8*)&Bsh[cur][(wn_ + i * 16 + ln) * BK + xs];
    }
    if constexpr (NPROD == 3) {
      short8 fal[4], fbl[4];
      #pragma unroll
      for (int i = 0; i < 4; ++i) {
        fal[i] = *(const short8*)&Asl[cur][(wm_ + i * 16 + ln) * BK + xs];
        fbl[i] = *(const short8*)&Bsl[cur][(wn_ + i * 16 + ln) * BK + xs];
      }
      #pragma unroll
      for (int i = 0; i < 4; ++i)
        #pragma unroll
        for (int j = 0; j < 4; ++j) {
          acc[i][j] = __builtin_amdgcn_mfma_f32_16x16x32_bf16(fah[i], fbh[j], acc[i][j], 0, 0, 0);
          acc[i][j] = __builtin_amdgcn_mfma_f32_16x16x32_bf16(fah[i], fbl[j], acc[i][j], 0, 0, 0);
          acc[i][j] = __builtin_amdgcn_mfma_f32_16x16x32_bf16(fal[i], fbh[j], acc[i][j], 0, 0, 0);
        }
    } else {
      #pragma unroll
      for (int i = 0; i < 4; ++i)
        #pragma unroll
        for (int j = 0; j < 4; ++j)
          acc[i][j] = __builtin_amdgcn_mfma_f32_16x16x32_bf16(fah[i], fbh[j], acc[i][j], 0, 0, 0);
    }
    __syncthreads();   // drains this iter's STAGE (vmcnt) + all LDS reads
    cur ^= 1;
  }

  // epilogue: C/D layout col=lane&15, row=(lane>>4)*4+reg (m89-verified)
  float* Cp;
  int ldc, cb;
  if (bn < Nq) { Cp = Cq + bz * zstride; ldc = ldq; cb = bn; }
  else         { Cp = Cv;                ldc = ldv; cb = bn - Nq; }
  #pragma unroll
  for (int i = 0; i < 4; ++i)
    #pragma unroll
    for (int j = 0; j < 4; ++j)
      #pragma unroll
      for (int rg = 0; rg < 4; ++rg) {
        int row = bm + wm_ + i * 16 + kg * 4 + rg;
        int col = cb + wn_ + j * 16 + ln;
        Cp[(size_t)row * ldc + col] = acc[i][j][rg];
      }
}

// --------------------------------------------- split-K reduce: out += p0 + p1
__global__ __launch_bounds__(256) void redadd(
    const float* __restrict__ p0, const float* __restrict__ p1,
    float* __restrict__ out) {
  const int n4 = T_DIM * (D_DIM / 4);
  for (int p = blockIdx.x * 256 + threadIdx.x; p < n4; p += gridDim.x * 256) {
    size_t i = (size_t)p * 4;
    float4 a = *(const float4*)(p0 + i);
    float4 b = *(const float4*)(p1 + i);
    float4 c = *(const float4*)(out + i);
    c.x += a.x + b.x; c.y += a.y + b.y; c.z += a.z + b.z; c.w += a.w + b.w;
    *(float4*)(out + i) = c;
  }
}

// ------------------------------------------------- per-chunk  sum k_s (x) v_s
__global__ __launch_bounds__(256) void chunk_kv_sums(
    const float* __restrict__ Km, int ldk,
    const float* __restrict__ Vm, int ldv, float* __restrict__ S) {
  __shared__ float Ks[CHUNK][DH];
  __shared__ float Vs[CHUNK][DH];
  const int c = blockIdx.x, hh = blockIdx.y, tid = threadIdx.x;
  #pragma unroll
  for (int l = 0; l < 4; ++l) {
    int idx = tid + l * 256;
    int s = idx >> 4, c4 = (idx & 15) << 2;
    *(float4*)&Ks[s][c4] = *(const float4*)(Km + (size_t)(c * CHUNK + s) * ldk + hh * DH + c4);
    *(float4*)&Vs[s][c4] = *(const float4*)(Vm + (size_t)(c * CHUNK + s) * ldv + hh * DH + c4);
  }
  __syncthreads();
  const int i0 = (tid >> 4) << 2;
  const int j0 = (tid & 15) << 2;
  float acc[4][4] = {};
  for (int s = 0; s < CHUNK; ++s) {
    float kv[4], vv[4];
    *(float4*)kv = *(const float4*)&Ks[s][i0];
    *(float4*)vv = *(const float4*)&Vs[s][j0];
    #pragma unroll
    for (int ii = 0; ii < 4; ++ii)
      #pragma unroll
      for (int jj = 0; jj < 4; ++jj)
        acc[ii][jj] = fmaf(kv[ii], vv[jj], acc[ii][jj]);
  }
  const size_t base = ((size_t)c * H_DIM + hh) * (DH * DH);
  #pragma unroll
  for (int ii = 0; ii < 4; ++ii)
    *(float4*)&S[base + (size_t)(i0 + ii) * DH + j0] =
        make_float4(acc[ii][0], acc[ii][1], acc[ii][2], acc[ii][3]);
}

// --------------------------- exclusive prefix over chunks (in place) + final
__global__ __launch_bounds__(256) void state_scan(
    const float* __restrict__ st0, const float* __restrict__ gamma,
    float* __restrict__ S, float* __restrict__ fs_out) {
  const int hh = blockIdx.y;
  const int e = blockIdx.x * 256 + threadIdx.x;
  float run = st0[(size_t)hh * 4096 + e];
  for (int c = 0; c < NCHUNK; ++c) {
    size_t idx = ((size_t)c * H_DIM + hh) * 4096 + e;
    float tmp = S[idx];
    S[idx] = run;
    run += tmp;
  }
  const int i = e >> 6;
  fs_out[(size_t)hh * 4096 + e] = run + (float)T_DIM * gamma[hh * DH + i];
}

// ------------------------------------------------------- per-chunk attention
// O may alias Vm (in-place): block (c,h) fully reads its V tile into LDS
// before writing O, and no other block touches that tile.
__global__ __launch_bounds__(256) void attn_intra(
    const float* __restrict__ Qm, int ldq,
    const float* __restrict__ Km, int ldk,
    const float* Vm, int ldv,
    const float* __restrict__ M, const float* __restrict__ gamma,
    float* O, int ldo) {
  __shared__ float Qs[CHUNK * DH];
  __shared__ float Bf[CHUNK * DH];
  __shared__ float As[CHUNK * CHUNK];
  __shared__ float Sq[CHUNK];
  const int c = blockIdx.x, hh = blockIdx.y, tid = threadIdx.x;

  #pragma unroll
  for (int l = 0; l < 4; ++l) {
    int idx = tid + l * 256;
    int r = idx >> 4, c4 = (idx & 15) << 2;
    *(float4*)&Qs[r * DH + c4] = *(const float4*)(Qm + (size_t)(c * CHUNK + r) * ldq + hh * DH + c4);
    float4 vv = *(const float4*)(Vm + (size_t)(c * CHUNK + r) * ldv + hh * DH + c4);
    Bf[(c4 + 0) * CHUNK + r] = vv.x;
    Bf[(c4 + 1) * CHUNK + r] = vv.y;
    Bf[(c4 + 2) * CHUNK + r] = vv.z;
    Bf[(c4 + 3) * CHUNK + r] = vv.w;
  }
  __syncthreads();
  if (tid < CHUNK) {
    float s = 0.f;
    for (int j = 0; j < DH; ++j) s += Qs[tid * DH + j];
    Sq[tid] = s;
  }
  #pragma unroll
  for (int rr = 0; rr < 16; ++rr) {
    int p = tid + rr * 256;
    int t = p >> 6, s = p & 63;
    float a = 0.f;
    for (int j = 0; j < DH; ++j)
      a = fmaf(Qs[t * DH + j], Bf[j * CHUNK + s], a);
    As[t * CHUNK + s] = a;
  }
  __syncthreads();
  #pragma unroll
  for (int l = 0; l < 4; ++l) {
    int idx = tid + l * 256;
    int r = idx >> 4, c4 = (idx & 15) << 2;
    *(float4*)&Bf[r * DH + c4] = *(const float4*)(Km + (size_t)(c * CHUNK + r) * ldk + hh * DH + c4);
  }
  __syncthreads();
  const int i = tid & 63, tg = tid >> 6;
  float acc[16];
  #pragma unroll
  for (int rr = 0; rr < 16; ++rr) {
    int t = rr * 4 + tg;
    float o = 0.f;
    for (int s = 0; s <= t; ++s)
      o = fmaf(As[t * CHUNK + s], Bf[s * DH + i], o);
    acc[rr] = o;
  }
  __syncthreads();
  #pragma unroll
  for (int l = 0; l < 4; ++l) {
    int idx = tid + l * 256;
    int r = idx >> 4, c4 = (idx & 15) << 2;
    size_t g = ((size_t)c * H_DIM + hh) * 4096 + (size_t)r * DH + c4;
    float4 mv = *(const float4*)(M + g);
    Bf[(c4 + 0) * DH + r] = mv.x;
    Bf[(c4 + 1) * DH + r] = mv.y;
    Bf[(c4 + 2) * DH + r] = mv.z;
    Bf[(c4 + 3) * DH + r] = mv.w;
  }
  __syncthreads();
  const float gi = gamma[hh * DH + i];
  #pragma unroll
  for (int rr = 0; rr < 16; ++rr) {
    int t = rr * 4 + tg;
    float o = acc[rr];
    for (int j = 0; j < DH; ++j)
      o = fmaf(Qs[t * DH + j], Bf[j * DH + i], o);
    o = fmaf((float)(c * CHUNK + t + 1) * gi, Sq[t], o);
    O[(size_t)(c * CHUNK + t) * ldo + hh * DH + i] = o;
  }
}

// ------------------------------------------------------------- gated SiLU
__device__ inline float sigf(float x) { return 1.0f / (1.0f + expf(-x)); }

__global__ __launch_bounds__(256) void gate_act(
    const float* __restrict__ G, ushort* __restrict__ Mh,
    ushort* Ml) {
  const int n4 = T_DIM * (D_DIM / 4);
  for (int p = blockIdx.x * 256 + threadIdx.x; p < n4; p += gridDim.x * 256) {
    int t = p / (D_DIM / 4);
    int d = (p % (D_DIM / 4)) * 4;
    size_t gbase = (size_t)t * (2 * D_DIM) + d;
    float4 gv = *(const float4*)(G + gbase);
    float4 mv = *(const float4*)(G + gbase + D_DIM);
    float rr[4];
    rr[0] = mv.x * sigf(mv.x) * sigf(gv.x);
    rr[1] = mv.y * sigf(mv.y) * sigf(gv.y);
    rr[2] = mv.z * sigf(mv.z) * sigf(gv.z);
    rr[3] = mv.w * sigf(mv.w) * sigf(gv.w);
    size_t off = (size_t)t * D_DIM + d;
    ushort h[4];
    #pragma unroll
    for (int j = 0; j < 4; ++j) h[j] = f2bf(rr[j]);
    *(ushort4*)(Mh + off) = make_ushort4(h[0], h[1], h[2], h[3]);
    if (Ml) {
      ushort lo[4];
      #pragma unroll
      for (int j = 0; j < 4; ++j) lo[j] = f2bf(rr[j] - bf2f(h[j]));
      *(ushort4*)(Ml + off) = make_ushort4(lo[0], lo[1], lo[2], lo[3]);
    }
  }
}

// ---------------------------------------------------------------- launcher
// TD = T*D = 8.39M elems, NK = D*D = 4.19M.  ws layout (4.5*TD floats = 144MB):
//   region0 [0,TD):      ACTh/ACTl (TD ush each) -> S (TD fp32) -> Mh
//   region1 [TD,2TD):    QK cols 0..2047 | G low | split-K partial P0
//   region2 [2TD,3TD):   QK cols 2048..4095 | G high | partial P1
//   region3 [3TD,4.5TD): WT hi|lo (QKV: 3NK+3NK ush)
// d_out[0,TD): V -> O -> Y -> final out.  fs_out at d_out[TD,..).
extern "C" void kernel_launch(void* const* d_in, const int* in_sizes, int n_in,
                              void* d_out, int out_size, void* d_ws, size_t ws_size,
                              hipStream_t stream) {
  const float* x     = (const float*)d_in[0];
  const float* st0   = (const float*)d_in[1];
  const float* Wq    = (const float*)d_in[2];
  const float* Wk    = (const float*)d_in[3];
  const float* Wv    = (const float*)d_in[4];
  const float* gamma = (const float*)d_in[5];
  const float* Wgate = (const float*)d_in[6];
  const float* Wdown = (const float*)d_in[7];
  const float* ln1w  = (const float*)d_in[8];
  const float* ln1b  = (const float*)d_in[9];
  const float* ln2w  = (const float*)d_in[10];
  const float* ln2b  = (const float*)d_in[11];

  const size_t TD = (size_t)T_DIM * D_DIM;
  const size_t NK = (size_t)D_DIM * D_DIM;
  if (ws_size < (TD * 9) / 2 * sizeof(float)) return;  // 4.5*TD guard

  float* out    = (float*)d_out;
  float* fs_out = out + TD;

  float* ws = (float*)d_ws;
  ushort* ACTh = (ushort*)ws;                  // region0
  ushort* ACTl = ACTh + TD;
  float*  S    = ws;                           // region0 (after QKV)
  ushort* Mh   = (ushort*)ws;                  // region0 (after gate_act)
  float*  QK   = ws + TD;                      // regions1+2: [T][4096]
  float*  G    = ws + TD;                      // regions1+2: [T][4096]
  float*  P0   = ws + TD;                      // split-K partials
  float*  P1   = ws + 2 * TD;
  ushort* WTh  = (ushort*)(ws + 3 * TD);       // region3
  float*  V    = out;                          // d_out[0,TD): V -> O -> Y
  float*  O    = out;
  float*  Y    = out;

  dim3 blk(256);
  dim3 tsq(32, 32);

  // ---- LN1 -> split activations (hi+lo: feeds 3-product QKV)
  ln_fwd<<<T_DIM, blk, 0, stream>>>(x, nullptr, nullptr, ln1w, ln1b, ACTh, ACTl);

  // ---- fused QKV GEMM (NPROD=3): WT = [Wq^T; Wk^T; Wv^T], N = 6144
  {
    ushort* WTl3 = WTh + 3 * NK;
    tsplit<<<tsq, blk, 0, stream>>>(Wq, WTh,          WTl3,          D_DIM, D_DIM);
    tsplit<<<tsq, blk, 0, stream>>>(Wk, WTh + NK,     WTl3 + NK,     D_DIM, D_DIM);
    tsplit<<<tsq, blk, 0, stream>>>(Wv, WTh + 2 * NK, WTl3 + 2 * NK, D_DIM, D_DIM);
    // cols [0,4096) -> QK (ld 4096); cols [4096,6144) -> V in d_out (ld 2048)
    gemm_bf16s<3><<<dim3(48, 32, 1), blk, 0, stream>>>(
        ACTh, ACTl, WTh, WTl3, QK, V, 2 * D_DIM, 2 * D_DIM, D_DIM,
        0, D_DIM, D_DIM);
  }

  // ---- linear-attention path (fp32); K at QK cols [2048,4096)
  chunk_kv_sums<<<dim3(NCHUNK, H_DIM), blk, 0, stream>>>(
      QK + D_DIM, 2 * D_DIM, V, D_DIM, S);
  state_scan<<<dim3(16, H_DIM), blk, 0, stream>>>(st0, gamma, S, fs_out);
  attn_intra<<<dim3(NCHUNK, H_DIM), blk, 0, stream>>>(
      QK, 2 * D_DIM, QK + D_DIM, 2 * D_DIM, V, D_DIM, S, gamma, O, D_DIM);

  // ---- Y = x + O (in d_out), ACT = bf16 LN2(Y)  (hi only: MLP is NPROD=1)
  ln_fwd<<<T_DIM, blk, 0, stream>>>(x, O, Y, ln2w, ln2b, ACTh, nullptr);

  // ---- MLP gate GEMM (NPROD=1, plain bf16): N = 4096 -> G
  {
    tsplit<<<dim3(64, 32), blk, 0, stream>>>(Wgate, WTh, nullptr, D_DIM, 2 * D_DIM);
    gemm_bf16s<1><<<dim3(32, 32, 1), blk, 0, stream>>>(
        ACTh, nullptr, WTh, nullptr, G, nullptr, 2 * D_DIM, 2 * D_DIM, 0,
        0, D_DIM, D_DIM);
  }
  gate_act<<<2048, blk, 0, stream>>>(G, Mh, nullptr);

  // ---- Wdown (NPROD=1) split-K=2 -> P0,P1; then out = Y + P0 + P1
  {
    tsplit<<<tsq, blk, 0, stream>>>(Wdown, WTh, nullptr, D_DIM, D_DIM);
    gemm_bf16s<1><<<dim3(16, 32, 2), blk, 0, stream>>>(
        Mh, nullptr, WTh, nullptr, P0, nullptr, D_DIM, D_DIM, 0,
        TD, D_DIM, D_DIM / 2);
    redadd<<<2048, blk, 0, stream>>>(P0, P1, out);
  }
}

// Round 11
// 722.321 us; speedup vs baseline: 1.6699x; 1.2636x over previous
//
#include <hip/hip_runtime.h>

#define T_DIM 4096
#define D_DIM 2048
#define H_DIM 32
#define DH    64
#define CHUNK 64
#define NCHUNK (T_DIM / CHUNK)
#define EPS 1e-5f
#define LTS 72   // LDS tile row stride (ushorts): 144B = 9*16B -> aligned, 2-way banks

typedef __attribute__((ext_vector_type(8))) short short8;
typedef __attribute__((ext_vector_type(4))) float f32x4;

// ----------------------------------------------------------- bf16 split utils
__device__ inline ushort f2bf(float f) {
  uint u = __float_as_uint(f);
  u += 0x7FFF + ((u >> 16) & 1);          // RNE
  return (ushort)(u >> 16);
}
__device__ inline float bf2f(ushort h) { return __uint_as_float(((uint)h) << 16); }
__device__ inline void split2(float f, ushort& hi, ushort& lo) {
  hi = f2bf(f);
  lo = f2bf(f - bf2f(hi));
}

// ------------------------------------------------------ global->LDS async DMA
__device__ __forceinline__ void gload16(const void* g, void* lds) {
  __builtin_amdgcn_global_load_lds(
      (const __attribute__((address_space(1))) unsigned int*)g,
      (__attribute__((address_space(3))) unsigned int*)lds, 16, 0, 0);
}

// -------------------------------- 64x64 fp32 tile -> split-bf16 LDS staging
// row-major: LDS[r][c] = g[r][c]
__device__ inline void stage_rm(const float* g, int ldg,
                                ushort* hiB, ushort* loB) {
  const int t = threadIdx.x;
  const int r = t >> 2, c0 = (t & 3) * 16;
  const float* src = g + (size_t)r * ldg + c0;
  #pragma unroll
  for (int b = 0; b < 4; ++b) {
    float4 v = *(const float4*)(src + b * 4);
    ushort h[4], l[4];
    split2(v.x, h[0], l[0]); split2(v.y, h[1], l[1]);
    split2(v.z, h[2], l[2]); split2(v.w, h[3], l[3]);
    *(ushort4*)&hiB[r * LTS + c0 + b * 4] = make_ushort4(h[0], h[1], h[2], h[3]);
    *(ushort4*)&loB[r * LTS + c0 + b * 4] = make_ushort4(l[0], l[1], l[2], l[3]);
  }
}
// transposed: LDS[c][r] = g[r][c]
__device__ inline void stage_tr(const float* g, int ldg,
                                ushort* hiB, ushort* loB) {
  const int t = threadIdx.x;
  const int r = t >> 2, c0 = (t & 3) * 16;
  const float* src = g + (size_t)r * ldg + c0;
  #pragma unroll
  for (int b = 0; b < 4; ++b) {
    float4 v = *(const float4*)(src + b * 4);
    ushort h[4], l[4];
    split2(v.x, h[0], l[0]); split2(v.y, h[1], l[1]);
    split2(v.z, h[2], l[2]); split2(v.w, h[3], l[3]);
    #pragma unroll
    for (int e = 0; e < 4; ++e) {
      hiB[(c0 + b * 4 + e) * LTS + r] = h[e];
      loB[(c0 + b * 4 + e) * LTS + r] = l[e];
    }
  }
}

// 3-product split-bf16 MFMA accumulate
__device__ inline f32x4 mfma3(const ushort* Ah_, const ushort* Al_,
                              const ushort* Bh_, const ushort* Bl_, f32x4 acc) {
  short8 ah = *(const short8*)Ah_;
  short8 al = *(const short8*)Al_;
  short8 bh = *(const short8*)Bh_;
  short8 bl = *(const short8*)Bl_;
  acc = __builtin_amdgcn_mfma_f32_16x16x32_bf16(ah, bh, acc, 0, 0, 0);
  acc = __builtin_amdgcn_mfma_f32_16x16x32_bf16(ah, bl, acc, 0, 0, 0);
  acc = __builtin_amdgcn_mfma_f32_16x16x32_bf16(al, bh, acc, 0, 0, 0);
  return acc;
}

// ---------------------------------------------------------------- LN helper
__device__ inline void block_reduce_2(float& s1, float& s2) {
  __shared__ float red[8];
  #pragma unroll
  for (int off = 32; off > 0; off >>= 1) {
    s1 += __shfl_down(s1, off, 64);
    s2 += __shfl_down(s2, off, 64);
  }
  int lane = threadIdx.x & 63, wid = threadIdx.x >> 6;
  if (lane == 0) { red[wid] = s1; red[4 + wid] = s2; }
  __syncthreads();
  s1 = red[0] + red[1] + red[2] + red[3];
  s2 = red[4] + red[5] + red[6] + red[7];
}

// LN; emits bf16 hi (and lo if out_lo != null). If Add: input = X+Add,
// pre-LN sum stored fp32 to Yout (Yout may alias Add: same-thread RBW).
__global__ __launch_bounds__(256) void ln_fwd(
    const float* __restrict__ X, const float* Add, float* Yout,
    const float* __restrict__ w, const float* __restrict__ b,
    ushort* __restrict__ out_hi, ushort* out_lo) {
  const int row = blockIdx.x;
  const size_t base = (size_t)row * D_DIM;
  const int t = threadIdx.x;

  float4 v0 = *(const float4*)(X + base + (size_t)t * 4);
  float4 v1 = *(const float4*)(X + base + (size_t)(t + 256) * 4);
  if (Add) {
    float4 a0 = *(const float4*)(Add + base + (size_t)t * 4);
    float4 a1 = *(const float4*)(Add + base + (size_t)(t + 256) * 4);
    v0.x += a0.x; v0.y += a0.y; v0.z += a0.z; v0.w += a0.w;
    v1.x += a1.x; v1.y += a1.y; v1.z += a1.z; v1.w += a1.w;
    *(float4*)(Yout + base + (size_t)t * 4) = v0;
    *(float4*)(Yout + base + (size_t)(t + 256) * 4) = v1;
  }
  float s  = v0.x + v0.y + v0.z + v0.w + v1.x + v1.y + v1.z + v1.w;
  float ss = v0.x*v0.x + v0.y*v0.y + v0.z*v0.z + v0.w*v0.w
           + v1.x*v1.x + v1.y*v1.y + v1.z*v1.z + v1.w*v1.w;
  block_reduce_2(s, ss);
  const float m   = s * (1.0f / D_DIM);
  const float var = ss * (1.0f / D_DIM) - m * m;
  const float r   = rsqrtf(var + EPS);

  float4 w0 = *(const float4*)(w + (size_t)t * 4);
  float4 w1 = *(const float4*)(w + (size_t)(t + 256) * 4);
  float4 b0 = *(const float4*)(b + (size_t)t * 4);
  float4 b1 = *(const float4*)(b + (size_t)(t + 256) * 4);
  float o[8];
  o[0] = (v0.x - m) * r * w0.x + b0.x;
  o[1] = (v0.y - m) * r * w0.y + b0.y;
  o[2] = (v0.z - m) * r * w0.z + b0.z;
  o[3] = (v0.w - m) * r * w0.w + b0.w;
  o[4] = (v1.x - m) * r * w1.x + b1.x;
  o[5] = (v1.y - m) * r * w1.y + b1.y;
  o[6] = (v1.z - m) * r * w1.z + b1.z;
  o[7] = (v1.w - m) * r * w1.w + b1.w;
  if (out_lo) {
    ushort h[8], l[8];
    #pragma unroll
    for (int j = 0; j < 8; ++j) split2(o[j], h[j], l[j]);
    *(ushort4*)(out_hi + base + (size_t)t * 4) = make_ushort4(h[0], h[1], h[2], h[3]);
    *(ushort4*)(out_lo + base + (size_t)t * 4) = make_ushort4(l[0], l[1], l[2], l[3]);
    *(ushort4*)(out_hi + base + (size_t)(t + 256) * 4) = make_ushort4(h[4], h[5], h[6], h[7]);
    *(ushort4*)(out_lo + base + (size_t)(t + 256) * 4) = make_ushort4(l[4], l[5], l[6], l[7]);
  } else {
    ushort h[8];
    #pragma unroll
    for (int j = 0; j < 8; ++j) h[j] = f2bf(o[j]);
    *(ushort4*)(out_hi + base + (size_t)t * 4) = make_ushort4(h[0], h[1], h[2], h[3]);
    *(ushort4*)(out_hi + base + (size_t)(t + 256) * 4) = make_ushort4(h[4], h[5], h[6], h[7]);
  }
}

// ----------------------------------- weight transpose + bf16 split (JIT, 64x64)
__global__ __launch_bounds__(256) void tsplit(
    const float* __restrict__ W, ushort* __restrict__ WTh,
    ushort* WTl, int KR, int NC) {
  __shared__ float tile[64][65];
  const int t = threadIdx.x;
  const int k0 = blockIdx.y * 64, n0 = blockIdx.x * 64;
  #pragma unroll
  for (int p = 0; p < 4; ++p) {
    int r = (t >> 4) + p * 16;
    int c = (t & 15) * 4;
    *(float4*)&tile[r][c] = *(const float4*)&W[(size_t)(k0 + r) * NC + n0 + c];
  }
  __syncthreads();
  #pragma unroll
  for (int p = 0; p < 4; ++p) {
    int n = (t >> 4) + p * 16;
    int c = (t & 15) * 4;
    size_t off = (size_t)(n0 + n) * KR + k0 + c;
    if (WTl) {
      ushort h[4], l[4];
      #pragma unroll
      for (int j = 0; j < 4; ++j) split2(tile[c + j][n], h[j], l[j]);
      *(ushort4*)(WTh + off) = make_ushort4(h[0], h[1], h[2], h[3]);
      *(ushort4*)(WTl + off) = make_ushort4(l[0], l[1], l[2], l[3]);
    } else {
      ushort h[4];
      #pragma unroll
      for (int j = 0; j < 4; ++j) h[j] = f2bf(tile[c + j][n]);
      *(ushort4*)(WTh + off) = make_ushort4(h[0], h[1], h[2], h[3]);
    }
  }
}

// --------------------- split-bf16 MFMA GEMM
// NPROD=3: single-buffered (occupancy wins; round-7-verified 274us).
// NPROD=1: 2-phase double-buffered (32KB LDS).
#define BM 128
#define BN 128
#define BK 32
template <int NPROD>
__global__ __launch_bounds__(256) void gemm_bf16s(
    const ushort* __restrict__ Ah, const ushort* __restrict__ Al,
    const ushort* __restrict__ Bh, const ushort* __restrict__ Bl,
    float* __restrict__ Cq, float* __restrict__ Cv,
    int Nq, int ldq, int ldv, size_t zstride, int K, int Klen) {
  constexpr int NBUF = (NPROD == 3) ? 1 : 2;
  __shared__ ushort Ash[NBUF][BM * BK];
  __shared__ ushort Bsh[NBUF][BN * BK];
  __shared__ ushort Asl[1][NPROD == 3 ? BM * BK : 16];
  __shared__ ushort Bsl[1][NPROD == 3 ? BN * BK : 16];
  const int tid = threadIdx.x;

  int bx, by, bz;
  {
    const int GX = gridDim.x, GY = gridDim.y;
    const int hwid = ((int)blockIdx.z * GY + (int)blockIdx.y) * GX + (int)blockIdx.x;
    const int BXC = GX >> 3;
    const int xcd = hwid & 7, s = hwid >> 3;
    const int bxl = s % BXC;
    const int t2 = s / BXC;
    by = t2 % GY;
    bz = t2 / GY;
    bx = xcd * BXC + bxl;
  }
  const int bm = by * BM, bn = bx * BN;
  const int koff = bz * Klen, kend = koff + Klen;

  const int l = tid & 63, wv = tid >> 6;
  const int lrow = l >> 2;
  const int q = (l & 3) ^ ((l >> 3) & 3);        // pre-swizzled global k-quarter
  const int ln = l & 15, kg = l >> 4;
  const int xs = (kg ^ ((ln >> 1) & 3)) * 8;     // swizzled frag slot
  const int wm_ = (wv >> 1) * 64, wn_ = (wv & 1) * 64;

  auto STAGE = [&](int buf, int k0) {
    size_t ga = (size_t)(bm + wv * 32 + lrow) * K + k0 + q * 8;
    gload16(Ah + ga,                  &Ash[buf][(wv * 32) * BK]);
    gload16(Ah + ga + 16 * (size_t)K, &Ash[buf][(wv * 32 + 16) * BK]);
    size_t gb = (size_t)(bn + wv * 32 + lrow) * K + k0 + q * 8;
    gload16(Bh + gb,                  &Bsh[buf][(wv * 32) * BK]);
    gload16(Bh + gb + 16 * (size_t)K, &Bsh[buf][(wv * 32 + 16) * BK]);
    if constexpr (NPROD == 3) {
      gload16(Al + ga,                  &Asl[0][(wv * 32) * BK]);
      gload16(Al + ga + 16 * (size_t)K, &Asl[0][(wv * 32 + 16) * BK]);
      gload16(Bl + gb,                  &Bsl[0][(wv * 32) * BK]);
      gload16(Bl + gb + 16 * (size_t)K, &Bsl[0][(wv * 32 + 16) * BK]);
    }
  };

  f32x4 acc[4][4];
  #pragma unroll
  for (int i = 0; i < 4; ++i)
    #pragma unroll
    for (int j = 0; j < 4; ++j) {
      f32x4 z = {0.f, 0.f, 0.f, 0.f};
      acc[i][j] = z;
    }

  if constexpr (NPROD == 3) {
    for (int k0 = koff; k0 < kend; k0 += BK) {
      STAGE(0, k0);
      __syncthreads();
      short8 fah[4], fal[4], fbh[4], fbl[4];
      #pragma unroll
      for (int i = 0; i < 4; ++i) {
        fah[i] = *(const short8*)&Ash[0][(wm_ + i * 16 + ln) * BK + xs];
        fal[i] = *(const short8*)&Asl[0][(wm_ + i * 16 + ln) * BK + xs];
        fbh[i] = *(const short8*)&Bsh[0][(wn_ + i * 16 + ln) * BK + xs];
        fbl[i] = *(const short8*)&Bsl[0][(wn_ + i * 16 + ln) * BK + xs];
      }
      #pragma unroll
      for (int i = 0; i < 4; ++i)
        #pragma unroll
        for (int j = 0; j < 4; ++j) {
          acc[i][j] = __builtin_amdgcn_mfma_f32_16x16x32_bf16(fah[i], fbh[j], acc[i][j], 0, 0, 0);
          acc[i][j] = __builtin_amdgcn_mfma_f32_16x16x32_bf16(fah[i], fbl[j], acc[i][j], 0, 0, 0);
          acc[i][j] = __builtin_amdgcn_mfma_f32_16x16x32_bf16(fal[i], fbh[j], acc[i][j], 0, 0, 0);
        }
      __syncthreads();
    }
  } else {
    STAGE(0, koff);
    __syncthreads();
    int cur = 0;
    for (int k0 = koff; k0 < kend; k0 += BK) {
      if (k0 + BK < kend) STAGE(cur ^ 1, k0 + BK);
      short8 fah[4], fbh[4];
      #pragma unroll
      for (int i = 0; i < 4; ++i) {
        fah[i] = *(const short8*)&Ash[cur][(wm_ + i * 16 + ln) * BK + xs];
        fbh[i] = *(const short8*)&Bsh[cur][(wn_ + i * 16 + ln) * BK + xs];
      }
      #pragma unroll
      for (int i = 0; i < 4; ++i)
        #pragma unroll
        for (int j = 0; j < 4; ++j)
          acc[i][j] = __builtin_amdgcn_mfma_f32_16x16x32_bf16(fah[i], fbh[j], acc[i][j], 0, 0, 0);
      __syncthreads();
      cur ^= 1;
    }
  }

  // epilogue (m89 C/D layout)
  float* Cp;
  int ldc, cb;
  if (bn < Nq) { Cp = Cq + bz * zstride; ldc = ldq; cb = bn; }
  else         { Cp = Cv;                ldc = ldv; cb = bn - Nq; }
  #pragma unroll
  for (int i = 0; i < 4; ++i)
    #pragma unroll
    for (int j = 0; j < 4; ++j)
      #pragma unroll
      for (int rg = 0; rg < 4; ++rg) {
        int row = bm + wm_ + i * 16 + kg * 4 + rg;
        int col = cb + wn_ + j * 16 + ln;
        Cp[(size_t)row * ldc + col] = acc[i][j][rg];
      }
}

// --------------------------------------------- split-K reduce: out += p0 + p1
__global__ __launch_bounds__(256) void redadd(
    const float* __restrict__ p0, const float* __restrict__ p1,
    float* __restrict__ out) {
  const int n4 = T_DIM * (D_DIM / 4);
  for (int p = blockIdx.x * 256 + threadIdx.x; p < n4; p += gridDim.x * 256) {
    size_t i = (size_t)p * 4;
    float4 a = *(const float4*)(p0 + i);
    float4 b = *(const float4*)(p1 + i);
    float4 c = *(const float4*)(out + i);
    c.x += a.x + b.x; c.y += a.y + b.y; c.z += a.z + b.z; c.w += a.w + b.w;
    *(float4*)(out + i) = c;
  }
}

// --------------------------- MFMA chunk sums: Mc[i][j] = sum_s K[s][i]V[s][j]
__global__ __launch_bounds__(256) void chunk_kv_mfma(
    const float* __restrict__ Km, int ldk,
    const float* __restrict__ Vm, int ldv, float* __restrict__ S) {
  __shared__ ushort Kth[64 * LTS], Ktl[64 * LTS];
  __shared__ ushort Vth[64 * LTS], Vtl[64 * LTS];
  const int c = blockIdx.x, hh = blockIdx.y, tid = threadIdx.x;
  stage_tr(Km + (size_t)(c * CHUNK) * ldk + hh * DH, ldk, Kth, Ktl);
  stage_tr(Vm + (size_t)(c * CHUNK) * ldv + hh * DH, ldv, Vth, Vtl);
  __syncthreads();
  const int l = tid & 63, wv = tid >> 6, ln = l & 15, kg = l >> 4;
  f32x4 acc[4];
  #pragma unroll
  for (int j = 0; j < 4; ++j) { f32x4 z = {0.f,0.f,0.f,0.f}; acc[j] = z; }
  #pragma unroll
  for (int ks = 0; ks < 2; ++ks) {
    const int ab = (wv * 16 + ln) * LTS + kg * 8 + ks * 32;
    #pragma unroll
    for (int js = 0; js < 4; ++js) {
      const int bb = (js * 16 + ln) * LTS + kg * 8 + ks * 32;
      acc[js] = mfma3(&Kth[ab], &Ktl[ab], &Vth[bb], &Vtl[bb], acc[js]);
    }
  }
  const size_t base = ((size_t)c * H_DIM + hh) * 4096;
  #pragma unroll
  for (int js = 0; js < 4; ++js)
    #pragma unroll
    for (int rg = 0; rg < 4; ++rg) {
      int i_ = wv * 16 + kg * 4 + rg, j_ = js * 16 + ln;
      S[base + (size_t)i_ * 64 + j_] = acc[js][rg];
    }
}

// --------------------------- exclusive prefix over chunks (in place) + final
__global__ __launch_bounds__(256) void state_scan(
    const float* __restrict__ st0, const float* __restrict__ gamma,
    float* __restrict__ S, float* __restrict__ fs_out) {
  const int hh = blockIdx.y;
  const int e = blockIdx.x * 256 + threadIdx.x;
  float run = st0[(size_t)hh * 4096 + e];
  for (int c = 0; c < NCHUNK; ++c) {
    size_t idx = ((size_t)c * H_DIM + hh) * 4096 + e;
    float tmp = S[idx];
    S[idx] = run;
    run += tmp;
  }
  const int i = e >> 6;
  fs_out[(size_t)hh * 4096 + e] = run + (float)T_DIM * gamma[hh * DH + i];
}

// ------------------------------------------------------- MFMA chunk attention
// o[t][i] = sum_{s<=t}(q_t.v_s) k_s[i] + sum_j M[i][j] q_t[j]
//           + (c*64+t+1)*gamma[i]*Sq[t]
// O may alias Vm: V staged to LDS before any O write; tile owned by one block.
__global__ __launch_bounds__(256) void attn_mfma(
    const float* __restrict__ Qm, int ldq,
    const float* __restrict__ Km, int ldk,
    const float* Vm, int ldv,
    const float* __restrict__ M, const float* __restrict__ gamma,
    float* O, int ldo) {
  __shared__ ushort Qh[64 * LTS], Ql[64 * LTS];
  __shared__ ushort VPh[64 * LTS], VPl[64 * LTS];   // V rows, then P (scores)
  __shared__ ushort Kth[64 * LTS], Ktl[64 * LTS];   // K transposed
  __shared__ ushort Mh_[64 * LTS], Ml_[64 * LTS];   // M rows
  __shared__ float Sq[64];
  __shared__ float gml[64];
  const int c = blockIdx.x, hh = blockIdx.y, tid = threadIdx.x;

  stage_rm(Qm + (size_t)(c * CHUNK) * ldq + hh * DH, ldq, Qh, Ql);
  stage_rm(Vm + (size_t)(c * CHUNK) * ldv + hh * DH, ldv, VPh, VPl);
  stage_tr(Km + (size_t)(c * CHUNK) * ldk + hh * DH, ldk, Kth, Ktl);
  stage_rm(M + ((size_t)c * H_DIM + hh) * 4096, 64, Mh_, Ml_);
  if (tid < 64) gml[tid] = gamma[hh * DH + tid];
  __syncthreads();
  if (tid < 64) {
    float s = 0.f;
    for (int j = 0; j < 64; ++j)
      s += bf2f(Qh[tid * LTS + j]) + bf2f(Ql[tid * LTS + j]);
    Sq[tid] = s;
  }

  const int l = tid & 63, wv = tid >> 6, ln = l & 15, kg = l >> 4;
  f32x4 accS[4], accO[4];
  #pragma unroll
  for (int j = 0; j < 4; ++j) {
    f32x4 z = {0.f, 0.f, 0.f, 0.f};
    accS[j] = z; accO[j] = z;
  }

  // G1: scores = Q @ V^T ; G3: O2 = Q @ M^T
  #pragma unroll
  for (int ks = 0; ks < 2; ++ks) {
    const int ab = (wv * 16 + ln) * LTS + kg * 8 + ks * 32;
    #pragma unroll
    for (int js = 0; js < 4; ++js) {
      const int bb = (js * 16 + ln) * LTS + kg * 8 + ks * 32;
      accS[js] = mfma3(&Qh[ab], &Ql[ab], &VPh[bb], &VPl[bb], accS[js]);
      accO[js] = mfma3(&Qh[ab], &Ql[ab], &Mh_[bb], &Ml_[bb], accO[js]);
    }
  }
  __syncthreads();   // all waves done reading V; Sq visible

  // causal mask + write P (split bf16) over the V buffer
  #pragma unroll
  for (int js = 0; js < 4; ++js)
    #pragma unroll
    for (int rg = 0; rg < 4; ++rg) {
      int t_ = wv * 16 + kg * 4 + rg, s_ = js * 16 + ln;
      float v = (s_ <= t_) ? accS[js][rg] : 0.f;
      ushort h, lo;
      split2(v, h, lo);
      VPh[t_ * LTS + s_] = h;
      VPl[t_ * LTS + s_] = lo;
    }
  __syncthreads();

  // G2: O1 = P @ K^T, accumulate into accO
  #pragma unroll
  for (int ks = 0; ks < 2; ++ks) {
    const int ab = (wv * 16 + ln) * LTS + kg * 8 + ks * 32;
    #pragma unroll
    for (int js = 0; js < 4; ++js) {
      const int bb = (js * 16 + ln) * LTS + kg * 8 + ks * 32;
      accO[js] = mfma3(&VPh[ab], &VPl[ab], &Kth[bb], &Ktl[bb], accO[js]);
    }
  }

  // epilogue: + (c*64+t+1)*gamma[i]*Sq[t], write O
  #pragma unroll
  for (int js = 0; js < 4; ++js)
    #pragma unroll
    for (int rg = 0; rg < 4; ++rg) {
      int t_ = wv * 16 + kg * 4 + rg, i_ = js * 16 + ln;
      float o = accO[js][rg] + (float)(c * CHUNK + t_ + 1) * gml[i_] * Sq[t_];
      O[(size_t)(c * CHUNK + t_) * ldo + hh * DH + i_] = o;
    }
}

// ------------------------------------------------------------- gated SiLU
__device__ inline float sigf(float x) { return 1.0f / (1.0f + expf(-x)); }

__global__ __launch_bounds__(256) void gate_act(
    const float* __restrict__ G, ushort* __restrict__ Mh, ushort* Ml) {
  const int n4 = T_DIM * (D_DIM / 4);
  for (int p = blockIdx.x * 256 + threadIdx.x; p < n4; p += gridDim.x * 256) {
    int t = p / (D_DIM / 4);
    int d = (p % (D_DIM / 4)) * 4;
    size_t gbase = (size_t)t * (2 * D_DIM) + d;
    float4 gv = *(const float4*)(G + gbase);
    float4 mv = *(const float4*)(G + gbase + D_DIM);
    float rr[4];
    rr[0] = mv.x * sigf(mv.x) * sigf(gv.x);
    rr[1] = mv.y * sigf(mv.y) * sigf(gv.y);
    rr[2] = mv.z * sigf(mv.z) * sigf(gv.z);
    rr[3] = mv.w * sigf(mv.w) * sigf(gv.w);
    size_t off = (size_t)t * D_DIM + d;
    ushort h[4];
    #pragma unroll
    for (int j = 0; j < 4; ++j) h[j] = f2bf(rr[j]);
    *(ushort4*)(Mh + off) = make_ushort4(h[0], h[1], h[2], h[3]);
    if (Ml) {
      ushort lo[4];
      #pragma unroll
      for (int j = 0; j < 4; ++j) lo[j] = f2bf(rr[j] - bf2f(h[j]));
      *(ushort4*)(Ml + off) = make_ushort4(lo[0], lo[1], lo[2], lo[3]);
    }
  }
}

// ---------------------------------------------------------------- launcher
// ws layout (4.5*TD floats = 144MB): region0 ACT/S/Mh; region1+2 QK|G|P0,P1;
// region3 WT. d_out[0,TD): V -> O -> Y -> out. fs_out at d_out[TD,..).
extern "C" void kernel_launch(void* const* d_in, const int* in_sizes, int n_in,
                              void* d_out, int out_size, void* d_ws, size_t ws_size,
                              hipStream_t stream) {
  const float* x     = (const float*)d_in[0];
  const float* st0   = (const float*)d_in[1];
  const float* Wq    = (const float*)d_in[2];
  const float* Wk    = (const float*)d_in[3];
  const float* Wv    = (const float*)d_in[4];
  const float* gamma = (const float*)d_in[5];
  const float* Wgate = (const float*)d_in[6];
  const float* Wdown = (const float*)d_in[7];
  const float* ln1w  = (const float*)d_in[8];
  const float* ln1b  = (const float*)d_in[9];
  const float* ln2w  = (const float*)d_in[10];
  const float* ln2b  = (const float*)d_in[11];

  const size_t TD = (size_t)T_DIM * D_DIM;
  const size_t NK = (size_t)D_DIM * D_DIM;
  if (ws_size < (TD * 9) / 2 * sizeof(float)) return;

  float* out    = (float*)d_out;
  float* fs_out = out + TD;

  float* ws = (float*)d_ws;
  ushort* ACTh = (ushort*)ws;
  ushort* ACTl = ACTh + TD;
  float*  S    = ws;
  ushort* Mh   = (ushort*)ws;
  float*  QK   = ws + TD;
  float*  G    = ws + TD;
  float*  P0   = ws + TD;
  float*  P1   = ws + 2 * TD;
  ushort* WTh  = (ushort*)(ws + 3 * TD);
  float*  V    = out;
  float*  O    = out;
  float*  Y    = out;

  dim3 blk(256);
  dim3 tsq(32, 32);

  // ---- LN1 -> split activations
  ln_fwd<<<T_DIM, blk, 0, stream>>>(x, nullptr, nullptr, ln1w, ln1b, ACTh, ACTl);

  // ---- fused QKV GEMM (NPROD=3, single-buffered)
  {
    ushort* WTl3 = WTh + 3 * NK;
    tsplit<<<tsq, blk, 0, stream>>>(Wq, WTh,          WTl3,          D_DIM, D_DIM);
    tsplit<<<tsq, blk, 0, stream>>>(Wk, WTh + NK,     WTl3 + NK,     D_DIM, D_DIM);
    tsplit<<<tsq, blk, 0, stream>>>(Wv, WTh + 2 * NK, WTl3 + 2 * NK, D_DIM, D_DIM);
    gemm_bf16s<3><<<dim3(48, 32, 1), blk, 0, stream>>>(
        ACTh, ACTl, WTh, WTl3, QK, V, 2 * D_DIM, 2 * D_DIM, D_DIM,
        0, D_DIM, D_DIM);
  }

  // ---- linear-attention path (MFMA split-bf16)
  chunk_kv_mfma<<<dim3(NCHUNK, H_DIM), blk, 0, stream>>>(
      QK + D_DIM, 2 * D_DIM, V, D_DIM, S);
  state_scan<<<dim3(16, H_DIM), blk, 0, stream>>>(st0, gamma, S, fs_out);
  attn_mfma<<<dim3(NCHUNK, H_DIM), blk, 0, stream>>>(
      QK, 2 * D_DIM, QK + D_DIM, 2 * D_DIM, V, D_DIM, S, gamma, O, D_DIM);

  // ---- Y = x + O, ACT = bf16 LN2(Y) (hi only)
  ln_fwd<<<T_DIM, blk, 0, stream>>>(x, O, Y, ln2w, ln2b, ACTh, nullptr);

  // ---- MLP gate GEMM (NPROD=1, dbuf)
  {
    tsplit<<<dim3(64, 32), blk, 0, stream>>>(Wgate, WTh, nullptr, D_DIM, 2 * D_DIM);
    gemm_bf16s<1><<<dim3(32, 32, 1), blk, 0, stream>>>(
        ACTh, nullptr, WTh, nullptr, G, nullptr, 2 * D_DIM, 2 * D_DIM, 0,
        0, D_DIM, D_DIM);
  }
  gate_act<<<2048, blk, 0, stream>>>(G, Mh, nullptr);

  // ---- Wdown (NPROD=1) split-K=2 -> P0,P1; out = Y + P0 + P1
  {
    tsplit<<<tsq, blk, 0, stream>>>(Wdown, WTh, nullptr, D_DIM, D_DIM);
    gemm_bf16s<1><<<dim3(16, 32, 2), blk, 0, stream>>>(
        Mh, nullptr, WTh, nullptr, P0, nullptr, D_DIM, D_DIM, 0,
        TD, D_DIM, D_DIM / 2);
    redadd<<<2048, blk, 0, stream>>>(P0, P1, out);
  }
}